// Round 1
// baseline (4943.330 us; speedup 1.0000x reference)
//
#include <hip/hip_runtime.h>
#include <math.h>

// Problem constants
constexpr int Bb  = 128;
constexpr int Ll  = 196;
constexpr int ENCe= 512;
constexpr int Hh  = 512;
constexpr int Ee  = 256;
constexpr int Vv  = 10000;
constexpr int Tt  = 20;

#define DEV __device__ __forceinline__

DEV float sigm_f(float x) { return 1.f / (1.f + __expf(-x)); }
DEV float tanh_f(float x) {
    x = fminf(fmaxf(x, -15.f), 15.f);
    float e = __expf(2.f * x);
    return (e - 1.f) / (e + 1.f);
}

// ---------------------------------------------------------------------------
// Generic tiled fp32 GEMM: C[M,N] = act( A[M,K] @ W[K,N] + bias )
// Features:
//  - K-split: for k >= K1 read A2 / Wk2 instead (fused x@W_ih + h@W_hh)
//  - N-split: for n >= N1 read Wn2 / bias2 / ACT2 (fused dec_proj | gate)
// BM fixed 64. Requires M % 64 == 0, K % 16 == 0 (true for all our shapes).
// N edge guarded (V=10000).
// ---------------------------------------------------------------------------
template<int BN, int TM, int TN, int ACT1, int ACT2>
__global__ __launch_bounds__(256)
void gemm_k(const float* __restrict__ A, int lda,
            const float* __restrict__ A2, int lda2,
            const float* __restrict__ Wk, int ldw,
            const float* __restrict__ Wk2, int ldw2,
            int K1,
            const float* __restrict__ Wn2, int ldwn2,
            const float* __restrict__ bias, const float* __restrict__ bias2,
            int N1,
            float* __restrict__ C, long long ldc,
            int M, int N, int K)
{
    constexpr int BM = 64, BK = 16;
    constexpr int TX = BN / TN, TY = BM / TM;
    static_assert(TX * TY == 256, "bad tile config");
    __shared__ float As[BK][BM];
    __shared__ float Ws[BK][BN];

    const int tid = threadIdx.x;
    const int tx = tid % TX, ty = tid / TX;
    const int nb = blockIdx.x * BN, mb = blockIdx.y * BM;

    float acc[TM][TN] = {};

    // A tile load mapping: one float4 along K per thread
    const int am = tid >> 2;          // 0..63 (row in tile)
    const int ak = (tid & 3) * 4;     // 0,4,8,12

    // W tile load mapping
    const int wn = tid % BN;
    const int wk0 = tid / BN;
    constexpr int WKSTEP = 256 / BN;

    const bool nsplit = (Wn2 != nullptr) && (nb >= N1);
    const float* Wn_base = nsplit ? Wn2 : Wk;
    const int ldw_n = nsplit ? ldwn2 : ldw;
    const int ncol0 = nsplit ? (nb - N1) : nb;

    for (int k0 = 0; k0 < K; k0 += BK) {
        const float* Ap; int la; int kk;
        const float* Wp; int lw;
        if (Wk2 != nullptr && k0 >= K1) {
            Ap = A2; la = lda2; kk = k0 - K1; Wp = Wk2; lw = ldw2;
        } else {
            Ap = A;  la = lda;  kk = k0;      Wp = Wn_base; lw = ldw_n;
        }
        // load A tile (transposed into LDS)
        float4 av = *(const float4*)&Ap[(size_t)(mb + am) * la + kk + ak];
        As[ak + 0][am] = av.x;
        As[ak + 1][am] = av.y;
        As[ak + 2][am] = av.z;
        As[ak + 3][am] = av.w;
        // load W tile
        #pragma unroll
        for (int i = 0; i < BK / WKSTEP; ++i) {
            int kw = wk0 + i * WKSTEP;
            Ws[kw][wn] = (nb + wn < N) ? Wp[(size_t)(kk + kw) * lw + ncol0 + wn] : 0.f;
        }
        __syncthreads();
        #pragma unroll
        for (int k = 0; k < BK; ++k) {
            float a[TM], w[TN];
            #pragma unroll
            for (int i = 0; i < TM; ++i) a[i] = As[k][ty * TM + i];
            #pragma unroll
            for (int j = 0; j < TN; ++j) w[j] = Ws[k][tx * TN + j];
            #pragma unroll
            for (int i = 0; i < TM; ++i)
                #pragma unroll
                for (int j = 0; j < TN; ++j)
                    acc[i][j] = fmaf(a[i], w[j], acc[i][j]);
        }
        __syncthreads();
    }

    const float* bi = nsplit ? bias2 : bias;
    #pragma unroll
    for (int i = 0; i < TM; ++i) {
        int m = mb + ty * TM + i;
        #pragma unroll
        for (int j = 0; j < TN; ++j) {
            int n = nb + tx * TN + j;
            if (n < N) {
                float v = acc[i][j];
                if (bi) v += bi[nsplit ? (n - N1) : n];
                int act = nsplit ? ACT2 : ACT1;
                if (act == 1)      v = tanh_f(v);
                else if (act == 2) v = sigm_f(v);
                C[(size_t)m * ldc + n] = v;
            }
        }
    }
}

// ---------------------------------------------------------------------------
// feat_mean[b,e] = mean over l of img[b,l,e]
// ---------------------------------------------------------------------------
__global__ __launch_bounds__(256)
void featmean_k(const float* __restrict__ img, float* __restrict__ fm)
{
    int b = blockIdx.x, tid = threadIdx.x;
    const float* base = img + (size_t)b * Ll * ENCe;
    for (int e = tid; e < ENCe; e += 256) {
        float s = 0.f;
        for (int l = 0; l < Ll; ++l) s += base[l * ENCe + e];
        fm[b * ENCe + e] = s * (1.f / (float)Ll);
    }
}

// ---------------------------------------------------------------------------
// bcomb = b_ih + b_hh
// ---------------------------------------------------------------------------
__global__ void bcomb_k(const float* __restrict__ bih, const float* __restrict__ bhh,
                        float* __restrict__ bc)
{
    int i = blockIdx.x * 256 + threadIdx.x;
    if (i < 4 * Hh) bc[i] = bih[i] + bhh[i];
}

// ---------------------------------------------------------------------------
// Attention: per block b.
//  e_l  = sum_k tanh(enc_proj[b,l,k] + dec_proj[b,k]) * v_att[k]
//  alpha = softmax(e) ; context = alpha @ img_feat[b]
//  (b_v is a uniform shift -> irrelevant for softmax, dropped)
// dg = [dec_proj | gate] packed [B,1024]; dec part at [b*1024 + k]
// ---------------------------------------------------------------------------
__global__ __launch_bounds__(256)
void attn_k(const float* __restrict__ enc_proj, const float* __restrict__ dg,
            const float* __restrict__ v_att, const float* __restrict__ img,
            float* __restrict__ alphas, long long alpha_stride,
            float* __restrict__ ctx)
{
    int b = blockIdx.x, tid = threadIdx.x;
    __shared__ float dp[Hh];
    __shared__ float va[Hh];
    __shared__ float es[Ll];
    __shared__ float red[4];

    for (int i = tid; i < Hh; i += 256) {
        dp[i] = dg[b * 1024 + i];
        va[i] = v_att[i];
    }
    __syncthreads();

    const int wv = tid >> 6, ln = tid & 63;
    const float* ep = enc_proj + (size_t)b * Ll * Hh;
    for (int l = wv; l < Ll; l += 4) {
        const float* row = ep + l * Hh;
        float s = 0.f;
        #pragma unroll
        for (int r = 0; r < 8; ++r) {
            int k = r * 64 + ln;
            s += tanh_f(row[k] + dp[k]) * va[k];
        }
        #pragma unroll
        for (int o = 32; o; o >>= 1) s += __shfl_xor(s, o);
        if (ln == 0) es[l] = s;
    }
    __syncthreads();

    // softmax over es[0..195]
    float v = (tid < Ll) ? es[tid] : -1e30f;
    float m = v;
    #pragma unroll
    for (int o = 32; o; o >>= 1) m = fmaxf(m, __shfl_xor(m, o));
    if (ln == 0) red[wv] = m;
    __syncthreads();
    m = fmaxf(fmaxf(red[0], red[1]), fmaxf(red[2], red[3]));
    __syncthreads();
    float p = (tid < Ll) ? __expf(v - m) : 0.f;
    float s = p;
    #pragma unroll
    for (int o = 32; o; o >>= 1) s += __shfl_xor(s, o);
    if (ln == 0) red[wv] = s;
    __syncthreads();
    s = red[0] + red[1] + red[2] + red[3];
    float inv = 1.f / s;
    if (tid < Ll) {
        float a = p * inv;
        es[tid] = a;
        alphas[(size_t)b * alpha_stride + tid] = a;
    }
    __syncthreads();

    // context
    const float* ib = img + (size_t)b * Ll * ENCe;
    for (int e = tid; e < ENCe; e += 256) {
        float acc = 0.f;
        for (int l = 0; l < Ll; ++l) acc = fmaf(es[l], ib[l * ENCe + e], acc);
        ctx[b * ENCe + e] = acc;
    }
}

// ---------------------------------------------------------------------------
// x[b, :256] = emb[captions[b,t]] ; x[b, 256:768] = ctx[b]*gate[b]
// ---------------------------------------------------------------------------
__global__ void build_x_k(const float* __restrict__ emb, const int* __restrict__ captions,
                          const float* __restrict__ ctx, const float* __restrict__ dg,
                          float* __restrict__ x, int t)
{
    int i = blockIdx.x * 256 + threadIdx.x;
    if (i >= Bb * (Ee + ENCe)) return;
    int b = i / (Ee + ENCe), j = i % (Ee + ENCe);
    float v;
    if (j < Ee) {
        v = emb[(size_t)captions[b * Tt + t] * Ee + j];
    } else {
        int k = j - Ee;
        v = ctx[b * ENCe + k] * dg[b * 1024 + 512 + k];  // gate part of dg
    }
    x[i] = v;
}

// ---------------------------------------------------------------------------
// LSTM cell elementwise: gates [B, 4H] (i|f|g|o), in-place h,c update
// ---------------------------------------------------------------------------
__global__ void lstm_k(const float* __restrict__ gates, float* __restrict__ h,
                       float* __restrict__ c)
{
    int i = blockIdx.x * 256 + threadIdx.x;
    if (i >= Bb * Hh) return;
    int b = i / Hh, j = i % Hh;
    const float* g = gates + (size_t)b * 4 * Hh;
    float ig = sigm_f(g[j]);
    float fg = sigm_f(g[Hh + j]);
    float gg = tanh_f(g[2 * Hh + j]);
    float og = sigm_f(g[3 * Hh + j]);
    float cn = fg * c[i] + ig * gg;
    h[i] = og * tanh_f(cn);
    c[i] = cn;
}

// ---------------------------------------------------------------------------
extern "C" void kernel_launch(void* const* d_in, const int* in_sizes, int n_in,
                              void* d_out, int out_size, void* d_ws, size_t ws_size,
                              hipStream_t stream)
{
    const float* img    = (const float*)d_in[0];
    const float* W_h    = (const float*)d_in[1];
    const float* b_h    = (const float*)d_in[2];
    const float* W_c    = (const float*)d_in[3];
    const float* b_c    = (const float*)d_in[4];
    const float* W_gate = (const float*)d_in[5];
    const float* b_gate = (const float*)d_in[6];
    const float* emb    = (const float*)d_in[7];
    const float* W_ae   = (const float*)d_in[8];
    const float* b_ae   = (const float*)d_in[9];
    const float* W_ad   = (const float*)d_in[10];
    const float* b_ad   = (const float*)d_in[11];
    const float* v_att  = (const float*)d_in[12];
    // d_in[13] = b_v (softmax shift, unused)
    const float* W_ih   = (const float*)d_in[14];
    const float* b_ih   = (const float*)d_in[15];
    const float* W_hh   = (const float*)d_in[16];
    const float* b_hh   = (const float*)d_in[17];
    const float* W_out  = (const float*)d_in[18];
    const float* b_out  = (const float*)d_in[19];
    const int* captions = (const int*)d_in[20];
    // d_in[21] = max_len (fixed 20)

    float* out    = (float*)d_out;                       // [B,T,V]
    float* alphas = out + (size_t)Bb * Tt * Vv;          // [B,T,L]

    float* ws       = (float*)d_ws;
    float* enc_proj = ws;                                // 25088*512
    float* fm       = enc_proj + (size_t)Bb * Ll * Hh;   // 128*512
    float* h        = fm + Bb * ENCe;                    // 128*512
    float* c        = h + Bb * Hh;                       // 128*512
    float* dg       = c + Bb * Hh;                       // 128*1024 (dec_proj|gate)
    float* ctx      = dg + Bb * 1024;                    // 128*512
    float* x        = ctx + Bb * ENCe;                   // 128*768
    float* gates    = x + Bb * (Ee + ENCe);              // 128*2048
    float* bcomb    = gates + Bb * 4 * Hh;               // 2048

    dim3 blk(256);
    const int NOSPLIT = 0x40000000;

    featmean_k<<<Bb, blk, 0, stream>>>(img, fm);
    bcomb_k<<<(4 * Hh + 255) / 256, blk, 0, stream>>>(b_ih, b_hh, bcomb);

    // h0 = tanh(fm @ W_h + b_h) ; c0 = tanh(fm @ W_c + b_c)
    gemm_k<32, 2, 4, 1, 1><<<dim3(Hh / 32, Bb / 64), blk, 0, stream>>>(
        fm, ENCe, nullptr, 0, W_h, Hh, nullptr, 0, NOSPLIT,
        nullptr, 0, b_h, nullptr, NOSPLIT, h, Hh, Bb, Hh, ENCe);
    gemm_k<32, 2, 4, 1, 1><<<dim3(Hh / 32, Bb / 64), blk, 0, stream>>>(
        fm, ENCe, nullptr, 0, W_c, Hh, nullptr, 0, NOSPLIT,
        nullptr, 0, b_c, nullptr, NOSPLIT, c, Hh, Bb, Hh, ENCe);

    // enc_proj = img @ W_ae + b_ae   (25088 x 512 x 512)
    gemm_k<64, 4, 4, 0, 0><<<dim3(Hh / 64, (Bb * Ll) / 64), blk, 0, stream>>>(
        img, ENCe, nullptr, 0, W_ae, Hh, nullptr, 0, NOSPLIT,
        nullptr, 0, b_ae, nullptr, NOSPLIT, enc_proj, Hh, Bb * Ll, Hh, ENCe);

    for (int t = 0; t < Tt; ++t) {
        // dg = [h@W_ad + b_ad | sigmoid(h@W_gate + b_gate)]
        gemm_k<32, 2, 4, 0, 2><<<dim3(1024 / 32, Bb / 64), blk, 0, stream>>>(
            h, Hh, nullptr, 0, W_ad, Hh, nullptr, 0, NOSPLIT,
            W_gate, ENCe, b_ad, b_gate, 512, dg, 1024, Bb, 1024, Hh);

        attn_k<<<Bb, blk, 0, stream>>>(enc_proj, dg, v_att, img,
                                       alphas + (size_t)t * Ll, (long long)Tt * Ll, ctx);

        build_x_k<<<(Bb * (Ee + ENCe) + 255) / 256, blk, 0, stream>>>(
            emb, captions, ctx, dg, x, t);

        // gates = x @ W_ih + h @ W_hh + (b_ih+b_hh)
        gemm_k<32, 2, 4, 0, 0><<<dim3(4 * Hh / 32, Bb / 64), blk, 0, stream>>>(
            x, Ee + ENCe, h, Hh, W_ih, 4 * Hh, W_hh, 4 * Hh, Ee + ENCe,
            nullptr, 0, bcomb, nullptr, NOSPLIT, gates, 4 * Hh, Bb, 4 * Hh, Ee + ENCe + Hh);

        lstm_k<<<(Bb * Hh + 255) / 256, blk, 0, stream>>>(gates, h, c);

        // out_t = h @ W_out + b_out -> outs[:, t, :]
        gemm_k<64, 4, 4, 0, 0><<<dim3((Vv + 63) / 64, Bb / 64), blk, 0, stream>>>(
            h, Hh, nullptr, 0, W_out, Vv, nullptr, 0, NOSPLIT,
            nullptr, 0, b_out, nullptr, NOSPLIT, out + (size_t)t * Vv, (long long)Tt * Vv,
            Bb, Vv, Hh);
    }
}

// Round 2
// 3487.651 us; speedup vs baseline: 1.4174x; 1.4174x over previous
//
#include <hip/hip_runtime.h>
#include <math.h>

typedef unsigned short ushort_t;
typedef __attribute__((ext_vector_type(8))) short bf16x8;
typedef __attribute__((ext_vector_type(4))) float f32x4;

constexpr int Bb  = 128;
constexpr int Ll  = 196;
constexpr int ENCe= 512;
constexpr int Hh  = 512;
constexpr int Ee  = 256;
constexpr int Vv  = 10000;
constexpr int Tt  = 20;

#define DEV __device__ __forceinline__

DEV float sigm_f(float x) { return 1.f / (1.f + __expf(-x)); }
DEV float tanh_f(float x) {
    x = fminf(fmaxf(x, -15.f), 15.f);
    float e = __expf(2.f * x);
    return (e - 1.f) / (e + 1.f);
}
DEV ushort_t f2bf(float v) {
    unsigned u = __float_as_uint(v);
    return (ushort_t)((u + 0x7FFFu + ((u >> 16) & 1u)) >> 16);
}
DEV float bf2f(ushort_t h) { return __uint_as_float(((unsigned)h) << 16); }

// ---------------------------------------------------------------------------
// fp32 tiled GEMM (round-0, + OUTBF flag to emit bf16). Used for h0/c0 and
// enc_proj only.
// ---------------------------------------------------------------------------
template<int BN, int TM, int TN, int ACT1, int ACT2, int OUTBF>
__global__ __launch_bounds__(256)
void gemm_k(const float* __restrict__ A, int lda,
            const float* __restrict__ A2, int lda2,
            const float* __restrict__ Wk, int ldw,
            const float* __restrict__ Wk2, int ldw2,
            int K1,
            const float* __restrict__ Wn2, int ldwn2,
            const float* __restrict__ bias, const float* __restrict__ bias2,
            int N1,
            void* __restrict__ Cv, long long ldc,
            int M, int N, int K)
{
    constexpr int BM = 64, BK = 16;
    constexpr int TX = BN / TN, TY = BM / TM;
    static_assert(TX * TY == 256, "bad tile config");
    __shared__ float As[BK][BM];
    __shared__ float Ws[BK][BN];

    const int tid = threadIdx.x;
    const int tx = tid % TX, ty = tid / TX;
    const int nb = blockIdx.x * BN, mb = blockIdx.y * BM;

    float acc[TM][TN] = {};

    const int am = tid >> 2;
    const int ak = (tid & 3) * 4;
    const int wn = tid % BN;
    const int wk0 = tid / BN;
    constexpr int WKSTEP = 256 / BN;

    const bool nsplit = (Wn2 != nullptr) && (nb >= N1);
    const float* Wn_base = nsplit ? Wn2 : Wk;
    const int ldw_n = nsplit ? ldwn2 : ldw;
    const int ncol0 = nsplit ? (nb - N1) : nb;

    for (int k0 = 0; k0 < K; k0 += BK) {
        const float* Ap; int la; int kk;
        const float* Wp; int lw;
        if (Wk2 != nullptr && k0 >= K1) {
            Ap = A2; la = lda2; kk = k0 - K1; Wp = Wk2; lw = ldw2;
        } else {
            Ap = A;  la = lda;  kk = k0;      Wp = Wn_base; lw = ldw_n;
        }
        float4 av = *(const float4*)&Ap[(size_t)(mb + am) * la + kk + ak];
        As[ak + 0][am] = av.x;
        As[ak + 1][am] = av.y;
        As[ak + 2][am] = av.z;
        As[ak + 3][am] = av.w;
        #pragma unroll
        for (int i = 0; i < BK / WKSTEP; ++i) {
            int kw = wk0 + i * WKSTEP;
            Ws[kw][wn] = (nb + wn < N) ? Wp[(size_t)(kk + kw) * lw + ncol0 + wn] : 0.f;
        }
        __syncthreads();
        #pragma unroll
        for (int k = 0; k < BK; ++k) {
            float a[TM], w[TN];
            #pragma unroll
            for (int i = 0; i < TM; ++i) a[i] = As[k][ty * TM + i];
            #pragma unroll
            for (int j = 0; j < TN; ++j) w[j] = Ws[k][tx * TN + j];
            #pragma unroll
            for (int i = 0; i < TM; ++i)
                #pragma unroll
                for (int j = 0; j < TN; ++j)
                    acc[i][j] = fmaf(a[i], w[j], acc[i][j]);
        }
        __syncthreads();
    }

    const float* bi = nsplit ? bias2 : bias;
    #pragma unroll
    for (int i = 0; i < TM; ++i) {
        int m = mb + ty * TM + i;
        #pragma unroll
        for (int j = 0; j < TN; ++j) {
            int n = nb + tx * TN + j;
            if (n < N) {
                float v = acc[i][j];
                if (bi) v += bi[nsplit ? (n - N1) : n];
                int act = nsplit ? ACT2 : ACT1;
                if (act == 1)      v = tanh_f(v);
                else if (act == 2) v = sigm_f(v);
                if (OUTBF) ((ushort_t*)Cv)[(size_t)m * ldc + n] = f2bf(v);
                else       ((float*)Cv)[(size_t)m * ldc + n] = v;
            }
        }
    }
}

// ---------------------------------------------------------------------------
// MFMA bf16 split GEMM: C[M,N] = act( A @ B^T + bias ), A = Ahi+Alo bf16
// rows [M][lda]; B given TRANSPOSED as [N][ldb] bf16 (hi, optional lo).
// Split-3 when BLO: Ahi*Bhi + Alo*Bhi + Ahi*Blo (fp32-like accuracy).
// One wave = 16 cols x MT*16 rows. Block = 4 waves along N.
// mfma_f32_16x16x32_bf16 frags: A[row=lane&15][k=(lane>>4)*8+j],
// B[k][col=lane&15]; D: col=lane&15, row=(lane>>4)*4+reg.
// ---------------------------------------------------------------------------
template<int MT, int ACT1, int ACT2, bool BLO>
__global__ __launch_bounds__(256)
void mgemm_k(const ushort_t* __restrict__ Ahi, const ushort_t* __restrict__ Alo, int lda,
             const ushort_t* __restrict__ Bhi, const ushort_t* __restrict__ Blo, int ldb,
             const float* __restrict__ bias, const float* __restrict__ bias2, int N1,
             float* __restrict__ C, long long ldc, int N, int K)
{
    const int wv = threadIdx.x >> 6, lane = threadIdx.x & 63;
    const int n0 = (blockIdx.x * 4 + wv) * 16;
    if (n0 >= N) return;
    const int m0 = blockIdx.y * (MT * 16);
    const int col = lane & 15, kq = (lane >> 4) * 8;

    const ushort_t* bh = Bhi + (size_t)(n0 + col) * ldb + kq;
    const ushort_t* bl = BLO ? (Blo + (size_t)(n0 + col) * ldb + kq) : nullptr;
    const ushort_t* ah[MT];
    const ushort_t* al[MT];
    #pragma unroll
    for (int mt = 0; mt < MT; ++mt) {
        size_t off = (size_t)(m0 + mt * 16 + col) * lda + kq;
        ah[mt] = Ahi + off;
        al[mt] = Alo + off;
    }

    f32x4 acc[MT];
    #pragma unroll
    for (int mt = 0; mt < MT; ++mt) acc[mt] = (f32x4){0.f, 0.f, 0.f, 0.f};

    for (int k0 = 0; k0 < K; k0 += 32) {
        bf16x8 bfh = *(const bf16x8*)bh; bh += 32;
        bf16x8 bfl;
        if (BLO) { bfl = *(const bf16x8*)bl; bl += 32; }
        #pragma unroll
        for (int mt = 0; mt < MT; ++mt) {
            bf16x8 afh = *(const bf16x8*)ah[mt]; ah[mt] += 32;
            bf16x8 afl = *(const bf16x8*)al[mt]; al[mt] += 32;
            acc[mt] = __builtin_amdgcn_mfma_f32_16x16x32_bf16(afh, bfh, acc[mt], 0, 0, 0);
            acc[mt] = __builtin_amdgcn_mfma_f32_16x16x32_bf16(afl, bfh, acc[mt], 0, 0, 0);
            if (BLO)
                acc[mt] = __builtin_amdgcn_mfma_f32_16x16x32_bf16(afh, bfl, acc[mt], 0, 0, 0);
        }
    }

    const bool ns = (n0 >= N1);
    const int nc = n0 + col;
    float bv = ns ? (bias2 ? bias2[nc - N1] : 0.f) : (bias ? bias[nc] : 0.f);
    const int act = ns ? ACT2 : ACT1;
    #pragma unroll
    for (int mt = 0; mt < MT; ++mt)
        #pragma unroll
        for (int r = 0; r < 4; ++r) {
            int row = m0 + mt * 16 + (lane >> 4) * 4 + r;
            float v = acc[mt][r] + bv;
            if (act == 1)      v = tanh_f(v);
            else if (act == 2) v = sigm_f(v);
            C[(size_t)row * ldc + nc] = v;
        }
}

// ---------------------------------------------------------------------------
// Transpose + convert: W[K][N] fp32 -> Thi/Tlo [N][ldt] bf16 at col offset kofs
// ---------------------------------------------------------------------------
template<bool LO>
__global__ __launch_bounds__(256)
void convT_k(const float* __restrict__ W, int K, int N,
             ushort_t* __restrict__ Thi, ushort_t* __restrict__ Tlo,
             int ldt, int kofs)
{
    __shared__ float tile[64][65];
    int n0 = blockIdx.x * 64, k0 = blockIdx.y * 64;
    int c = threadIdx.x & 63, r0 = threadIdx.x >> 6;
    #pragma unroll
    for (int i = 0; i < 16; ++i) {
        int r = r0 * 16 + i;
        tile[r][c] = (n0 + c < N) ? W[(size_t)(k0 + r) * N + n0 + c] : 0.f;
    }
    __syncthreads();
    int nr = threadIdx.x >> 2, kc = (threadIdx.x & 3) * 16;
    if (n0 + nr < N) {
        ushort_t* ph = Thi + (size_t)(n0 + nr) * ldt + kofs + k0 + kc;
        ushort_t* pl = LO ? (Tlo + (size_t)(n0 + nr) * ldt + kofs + k0 + kc) : nullptr;
        #pragma unroll
        for (int j = 0; j < 16; ++j) {
            float v = tile[kc + j][nr];
            ushort_t h = f2bf(v);
            ph[j] = h;
            if (LO) pl[j] = f2bf(v - bf2f(h));
        }
    }
}

// elementwise fp32 -> bf16
__global__ void convbf_k(const float* __restrict__ src, ushort_t* __restrict__ dst,
                         long long n)
{
    long long i = (long long)(blockIdx.x * 256 + threadIdx.x) * 4;
    long long stride = (long long)gridDim.x * 1024;
    for (; i + 3 < n; i += stride) {
        float4 v = *(const float4*)&src[i];
        dst[i + 0] = f2bf(v.x); dst[i + 1] = f2bf(v.y);
        dst[i + 2] = f2bf(v.z); dst[i + 3] = f2bf(v.w);
    }
}

// feat_mean
__global__ __launch_bounds__(256)
void featmean_k(const float* __restrict__ img, float* __restrict__ fm)
{
    int b = blockIdx.x, tid = threadIdx.x;
    const float* base = img + (size_t)b * Ll * ENCe;
    for (int e = tid; e < ENCe; e += 256) {
        float s = 0.f;
        for (int l = 0; l < Ll; ++l) s += base[l * ENCe + e];
        fm[b * ENCe + e] = s * (1.f / (float)Ll);
    }
}

__global__ void bcomb_k(const float* __restrict__ bih, const float* __restrict__ bhh,
                        float* __restrict__ bc)
{
    int i = blockIdx.x * 256 + threadIdx.x;
    if (i < 4 * Hh) bc[i] = bih[i] + bhh[i];
}

// h fp32 -> xh hi/lo at col 768
__global__ void hconv_k(const float* __restrict__ h, ushort_t* __restrict__ xhi,
                        ushort_t* __restrict__ xlo)
{
    int i = blockIdx.x * 256 + threadIdx.x;
    if (i >= Bb * Hh) return;
    int b = i / Hh, j = i % Hh;
    float v = h[i];
    ushort_t hb = f2bf(v);
    xhi[b * 1280 + 768 + j] = hb;
    xlo[b * 1280 + 768 + j] = f2bf(v - bf2f(hb));
}

// ---------------------------------------------------------------------------
// Attention scores: e[b][l] = sum_k tanh(enc[b,l,k] + dec[b,k]) * v_att[k]
// grid (B, 2): each block does 98 rows.
// ---------------------------------------------------------------------------
__global__ __launch_bounds__(256)
void attn_score_k(const ushort_t* __restrict__ enc, const float* __restrict__ dg,
                  const float* __restrict__ v_att, float* __restrict__ ebuf)
{
    int b = blockIdx.x, half = blockIdx.y;
    __shared__ float dp[Hh], va[Hh];
    for (int i = threadIdx.x; i < Hh; i += 256) {
        dp[i] = dg[b * 1024 + i];
        va[i] = v_att[i];
    }
    __syncthreads();
    int wv = threadIdx.x >> 6, ln = threadIdx.x & 63;
    int lbase = half * 98;
    const ushort_t* ep = enc + (size_t)b * Ll * Hh;
    for (int l = lbase + wv; l < lbase + 98; l += 4) {
        const ushort_t* row = ep + (size_t)l * Hh;
        float s = 0.f;
        #pragma unroll
        for (int r = 0; r < 8; ++r) {
            int k = r * 64 + ln;
            s += tanh_f(bf2f(row[k]) + dp[k]) * va[k];
        }
        #pragma unroll
        for (int o = 32; o; o >>= 1) s += __shfl_xor(s, o);
        if (ln == 0) ebuf[b * Ll + l] = s;
    }
}

// ---------------------------------------------------------------------------
// Softmax over L + write alphas + fused emb -> x[0:256] hi/lo.
// ---------------------------------------------------------------------------
__global__ __launch_bounds__(256)
void attn_soft_k(const float* __restrict__ ebuf, float* __restrict__ alphas,
                 long long alpha_stride, float* __restrict__ aw,
                 const float* __restrict__ emb, const int* __restrict__ captions,
                 ushort_t* __restrict__ xhi, ushort_t* __restrict__ xlo, int t)
{
    int b = blockIdx.x, tid = threadIdx.x;
    int wv = tid >> 6, ln = tid & 63;
    __shared__ float red[4];

    float v = (tid < Ll) ? ebuf[b * Ll + tid] : -1e30f;
    float m = v;
    #pragma unroll
    for (int o = 32; o; o >>= 1) m = fmaxf(m, __shfl_xor(m, o));
    if (ln == 0) red[wv] = m;
    __syncthreads();
    m = fmaxf(fmaxf(red[0], red[1]), fmaxf(red[2], red[3]));
    __syncthreads();
    float p = (tid < Ll) ? __expf(v - m) : 0.f;
    float s = p;
    #pragma unroll
    for (int o = 32; o; o >>= 1) s += __shfl_xor(s, o);
    if (ln == 0) red[wv] = s;
    __syncthreads();
    s = red[0] + red[1] + red[2] + red[3];
    float inv = 1.f / s;
    if (tid < Ll) {
        float a = p * inv;
        aw[b * Ll + tid] = a;
        alphas[(size_t)b * alpha_stride + tid] = a;
    }
    // fused: x[b][0:256] = emb[captions[b,t]]
    float xv = emb[(size_t)captions[b * Tt + t] * Ee + tid];
    ushort_t hb = f2bf(xv);
    xhi[b * 1280 + tid] = hb;
    xlo[b * 1280 + tid] = f2bf(xv - bf2f(hb));
}

// ---------------------------------------------------------------------------
// Context + gate + write x[256:768] hi/lo. grid (B, 2), 256 e-cols per block.
// ---------------------------------------------------------------------------
template<bool IMGBF>
__global__ __launch_bounds__(256)
void attn_ctx_k(const float* __restrict__ aw, const ushort_t* __restrict__ img_bf,
                const float* __restrict__ img_f, const float* __restrict__ dg,
                ushort_t* __restrict__ xhi, ushort_t* __restrict__ xlo)
{
    int b = blockIdx.x, half = blockIdx.y;
    __shared__ float a[Ll];
    for (int i = threadIdx.x; i < Ll; i += 256) a[i] = aw[b * Ll + i];
    __syncthreads();
    int e = half * 256 + threadIdx.x;
    float s = 0.f;
    if (IMGBF) {
        const ushort_t* ib = img_bf + (size_t)b * Ll * ENCe + e;
        for (int l = 0; l < Ll; ++l) s = fmaf(a[l], bf2f(ib[(size_t)l * ENCe]), s);
    } else {
        const float* ib = img_f + (size_t)b * Ll * ENCe + e;
        for (int l = 0; l < Ll; ++l) s = fmaf(a[l], ib[(size_t)l * ENCe], s);
    }
    float xv = s * dg[b * 1024 + 512 + e];
    ushort_t hb = f2bf(xv);
    int j = 256 + e;
    xhi[b * 1280 + j] = hb;
    xlo[b * 1280 + j] = f2bf(xv - bf2f(hb));
}

// LSTM elementwise; writes c and h (as bf16 hi/lo into xh[768:1280])
__global__ void lstm_k(const float* __restrict__ gates, float* __restrict__ c,
                       ushort_t* __restrict__ xhi, ushort_t* __restrict__ xlo)
{
    int i = blockIdx.x * 256 + threadIdx.x;
    if (i >= Bb * Hh) return;
    int b = i / Hh, j = i % Hh;
    const float* g = gates + (size_t)b * 4 * Hh;
    float ig = sigm_f(g[j]);
    float fg = sigm_f(g[Hh + j]);
    float gg = tanh_f(g[2 * Hh + j]);
    float og = sigm_f(g[3 * Hh + j]);
    float cn = fg * c[i] + ig * gg;
    c[i] = cn;
    float hv = og * tanh_f(cn);
    ushort_t hb = f2bf(hv);
    xhi[b * 1280 + 768 + j] = hb;
    xlo[b * 1280 + 768 + j] = f2bf(hv - bf2f(hb));
}

// ---------------------------------------------------------------------------
extern "C" void kernel_launch(void* const* d_in, const int* in_sizes, int n_in,
                              void* d_out, int out_size, void* d_ws, size_t ws_size,
                              hipStream_t stream)
{
    const float* img    = (const float*)d_in[0];
    const float* W_h    = (const float*)d_in[1];
    const float* b_h    = (const float*)d_in[2];
    const float* W_c    = (const float*)d_in[3];
    const float* b_c    = (const float*)d_in[4];
    const float* W_gate = (const float*)d_in[5];
    const float* b_gate = (const float*)d_in[6];
    const float* emb    = (const float*)d_in[7];
    const float* W_ae   = (const float*)d_in[8];
    const float* b_ae   = (const float*)d_in[9];
    const float* W_ad   = (const float*)d_in[10];
    const float* b_ad   = (const float*)d_in[11];
    const float* v_att  = (const float*)d_in[12];
    const float* W_ih   = (const float*)d_in[14];
    const float* b_ih   = (const float*)d_in[15];
    const float* W_hh   = (const float*)d_in[16];
    const float* b_hh   = (const float*)d_in[17];
    const float* W_out  = (const float*)d_in[18];
    const float* b_out  = (const float*)d_in[19];
    const int* captions = (const int*)d_in[20];

    float* out    = (float*)d_out;                       // [B,T,V]
    float* alphas = out + (size_t)Bb * Tt * Vv;          // [B,T,L]

    // ---- workspace allocator (256B aligned) ----
    char* p = (char*)d_ws;
    auto alloc = [&](size_t bytes) -> char* {
        char* r = p; p += (bytes + 255) & ~(size_t)255; return r;
    };
    const size_t szEnc   = (size_t)Bb * Ll * Hh * 2;      // 25.7 MB
    const size_t szWout  = (size_t)Vv * Hh * 2;           // 10.24 MB
    const size_t szWg    = (size_t)(4 * Hh) * 1280 * 2;   // 5.24 MB
    const size_t szWdg   = (size_t)1024 * Hh * 2;         // 1.05 MB
    const size_t szXh    = (size_t)Bb * 1280 * 2;         // 0.33 MB
    const size_t szImg   = (size_t)Bb * Ll * ENCe * 2;    // 25.7 MB

    ushort_t* enc_hi = (ushort_t*)alloc(szEnc);
    ushort_t* WoutH  = (ushort_t*)alloc(szWout);
    ushort_t* WgH    = (ushort_t*)alloc(szWg);
    ushort_t* WdgH   = (ushort_t*)alloc(szWdg);
    ushort_t* xhH    = (ushort_t*)alloc(szXh);
    ushort_t* xhL    = (ushort_t*)alloc(szXh);
    float*    cbuf   = (float*)alloc((size_t)Bb * Hh * 4);
    float*    dgb    = (float*)alloc((size_t)Bb * 1024 * 4);
    float*    S      = (float*)alloc((size_t)Bb * 2048 * 4); // gates/fm/ebuf/aw/h0 union
    float*    bcomb  = (float*)alloc(4 * Hh * 4);

    // optional tiers
    auto tryAlloc = [&](size_t bytes) -> char* {
        size_t used = (size_t)(p - (char*)d_ws);
        size_t rounded = (bytes + 255) & ~(size_t)255;
        if (used + rounded > ws_size) return nullptr;
        return alloc(bytes);
    };
    ushort_t* WoutL = (ushort_t*)tryAlloc(szWout);
    ushort_t* WgL   = (ushort_t*)tryAlloc(szWg);
    ushort_t* WdgL  = (ushort_t*)tryAlloc(szWdg);
    ushort_t* imgH  = (ushort_t*)tryAlloc(szImg);

    // union-region views
    float* ebuf = S;                     // [B][196]
    float* aw   = S + Bb * Ll;           // [B][196]
    float* fm   = S + 2 * Bb * Ll;       // [B][512]
    float* h0b  = fm + Bb * ENCe;        // [B][512]
    float* gates = S;                    // [B][2048] (overwrites the above later)

    dim3 blk(256);
    const int NOSPLIT = 0x40000000;

    // ---- one-time weight conversion (transposed bf16 hi/lo) ----
    if (WoutL) convT_k<true ><<<dim3(157, 8), blk, 0, stream>>>(W_out, Hh, Vv, WoutH, WoutL, Hh, 0);
    else       convT_k<false><<<dim3(157, 8), blk, 0, stream>>>(W_out, Hh, Vv, WoutH, nullptr, Hh, 0);
    if (WgL) {
        convT_k<true ><<<dim3(32, 12), blk, 0, stream>>>(W_ih, 768, 2048, WgH, WgL, 1280, 0);
        convT_k<true ><<<dim3(32, 8),  blk, 0, stream>>>(W_hh, Hh,  2048, WgH, WgL, 1280, 768);
    } else {
        convT_k<false><<<dim3(32, 12), blk, 0, stream>>>(W_ih, 768, 2048, WgH, nullptr, 1280, 0);
        convT_k<false><<<dim3(32, 8),  blk, 0, stream>>>(W_hh, Hh,  2048, WgH, nullptr, 1280, 768);
    }
    if (WdgL) {
        convT_k<true ><<<dim3(8, 8), blk, 0, stream>>>(W_ad,   Hh, Hh, WdgH, WdgL, Hh, 0);
        convT_k<true ><<<dim3(8, 8), blk, 0, stream>>>(W_gate, Hh, ENCe, WdgH + (size_t)512 * Hh,
                                                       WdgL + (size_t)512 * Hh, Hh, 0);
    } else {
        convT_k<false><<<dim3(8, 8), blk, 0, stream>>>(W_ad,   Hh, Hh, WdgH, nullptr, Hh, 0);
        convT_k<false><<<dim3(8, 8), blk, 0, stream>>>(W_gate, Hh, ENCe, WdgH + (size_t)512 * Hh,
                                                       nullptr, Hh, 0);
    }
    if (imgH)
        convbf_k<<<2048, blk, 0, stream>>>(img, imgH, (long long)Bb * Ll * ENCe);

    bcomb_k<<<(4 * Hh + 255) / 256, blk, 0, stream>>>(b_ih, b_hh, bcomb);
    featmean_k<<<Bb, blk, 0, stream>>>(img, fm);

    // h0 = tanh(fm @ W_h + b_h) ; c0 = tanh(fm @ W_c + b_c)
    gemm_k<32, 2, 4, 1, 1, 0><<<dim3(Hh / 32, Bb / 64), blk, 0, stream>>>(
        fm, ENCe, nullptr, 0, W_h, Hh, nullptr, 0, NOSPLIT,
        nullptr, 0, b_h, nullptr, NOSPLIT, h0b, Hh, Bb, Hh, ENCe);
    gemm_k<32, 2, 4, 1, 1, 0><<<dim3(Hh / 32, Bb / 64), blk, 0, stream>>>(
        fm, ENCe, nullptr, 0, W_c, Hh, nullptr, 0, NOSPLIT,
        nullptr, 0, b_c, nullptr, NOSPLIT, cbuf, Hh, Bb, Hh, ENCe);
    hconv_k<<<(Bb * Hh + 255) / 256, blk, 0, stream>>>(h0b, xhH, xhL);

    // enc_proj (bf16 output)
    gemm_k<64, 4, 4, 0, 0, 1><<<dim3(Hh / 64, (Bb * Ll) / 64), blk, 0, stream>>>(
        img, ENCe, nullptr, 0, W_ae, Hh, nullptr, 0, NOSPLIT,
        nullptr, 0, b_ae, nullptr, NOSPLIT, enc_hi, Hh, Bb * Ll, Hh, ENCe);

    const ushort_t* hH = xhH + 768;  // h rows inside xh, lda=1280
    const ushort_t* hL = xhL + 768;

    for (int t = 0; t < Tt; ++t) {
        // dg = [h@W_ad + b_ad | sigmoid(h@W_gate + b_gate)]
        if (WdgL)
            mgemm_k<2, 0, 2, true ><<<dim3(16, 4), blk, 0, stream>>>(
                hH, hL, 1280, WdgH, WdgL, Hh, b_ad, b_gate, 512, dgb, 1024, 1024, Hh);
        else
            mgemm_k<2, 0, 2, false><<<dim3(16, 4), blk, 0, stream>>>(
                hH, hL, 1280, WdgH, nullptr, Hh, b_ad, b_gate, 512, dgb, 1024, 1024, Hh);

        attn_score_k<<<dim3(Bb, 2), blk, 0, stream>>>(enc_hi, dgb, v_att, ebuf);
        attn_soft_k<<<Bb, blk, 0, stream>>>(ebuf, alphas + (size_t)t * Ll, (long long)Tt * Ll,
                                            aw, emb, captions, xhH, xhL, t);
        if (imgH)
            attn_ctx_k<true ><<<dim3(Bb, 2), blk, 0, stream>>>(aw, imgH, nullptr, dgb, xhH, xhL);
        else
            attn_ctx_k<false><<<dim3(Bb, 2), blk, 0, stream>>>(aw, nullptr, img, dgb, xhH, xhL);

        // gates = [x|h] @ [W_ih;W_hh]^T + bcomb
        if (WgL)
            mgemm_k<4, 0, 0, true ><<<dim3(32, 2), blk, 0, stream>>>(
                xhH, xhL, 1280, WgH, WgL, 1280, bcomb, nullptr, NOSPLIT,
                gates, 2048, 2048, 1280);
        else
            mgemm_k<4, 0, 0, false><<<dim3(32, 2), blk, 0, stream>>>(
                xhH, xhL, 1280, WgH, nullptr, 1280, bcomb, nullptr, NOSPLIT,
                gates, 2048, 2048, 1280);

        lstm_k<<<(Bb * Hh + 255) / 256, blk, 0, stream>>>(gates, cbuf, xhH, xhL);

        // logits
        if (WoutL)
            mgemm_k<4, 0, 0, true ><<<dim3(157, 2), blk, 0, stream>>>(
                hH, hL, 1280, WoutH, WoutL, Hh, b_out, nullptr, NOSPLIT,
                out + (size_t)t * Vv, (long long)Tt * Vv, Vv, Hh);
        else
            mgemm_k<4, 0, 0, false><<<dim3(157, 2), blk, 0, stream>>>(
                hH, hL, 1280, WoutH, nullptr, Hh, b_out, nullptr, NOSPLIT,
                out + (size_t)t * Vv, (long long)Tt * Vv, Vv, Hh);
    }
}

// Round 3
// 2337.661 us; speedup vs baseline: 2.1146x; 1.4919x over previous
//
#include <hip/hip_runtime.h>
#include <math.h>

typedef unsigned short ushort_t;
typedef __attribute__((ext_vector_type(8))) short bf16x8;
typedef __attribute__((ext_vector_type(4))) float f32x4;

constexpr int Bb  = 128;
constexpr int Ll  = 196;
constexpr int ENCe= 512;
constexpr int Hh  = 512;
constexpr int Ee  = 256;
constexpr int Vv  = 10000;
constexpr int Tt  = 20;

#define DEV __device__ __forceinline__

DEV float sigm_f(float x) { return 1.f / (1.f + __expf(-x)); }
DEV float tanh_f(float x) {
    x = fminf(fmaxf(x, -15.f), 15.f);
    float e = __expf(2.f * x);
    return (e - 1.f) / (e + 1.f);
}
DEV ushort_t f2bf(float v) {
    unsigned u = __float_as_uint(v);
    return (ushort_t)((u + 0x7FFFu + ((u >> 16) & 1u)) >> 16);
}
DEV float bf2f(ushort_t h) { return __uint_as_float(((unsigned)h) << 16); }

// ---------------------------------------------------------------------------
// fp32 tiled GEMM (h0/c0 + enc_proj fallback). OUTBF emits bf16.
// ---------------------------------------------------------------------------
template<int BN, int TM, int TN, int ACT1, int OUTBF>
__global__ __launch_bounds__(256)
void gemm_k(const float* __restrict__ A, int lda,
            const float* __restrict__ Wk, int ldw,
            const float* __restrict__ bias,
            void* __restrict__ Cv, long long ldc,
            int M, int N, int K)
{
    constexpr int BM = 64, BK = 16;
    constexpr int TX = BN / TN, TY = BM / TM;
    static_assert(TX * TY == 256, "bad tile config");
    __shared__ float As[BK][BM];
    __shared__ float Ws[BK][BN];

    const int tid = threadIdx.x;
    const int tx = tid % TX, ty = tid / TX;
    const int nb = blockIdx.x * BN, mb = blockIdx.y * BM;

    float acc[TM][TN] = {};
    const int am = tid >> 2;
    const int ak = (tid & 3) * 4;
    const int wn = tid % BN;
    const int wk0 = tid / BN;
    constexpr int WKSTEP = 256 / BN;

    for (int k0 = 0; k0 < K; k0 += BK) {
        float4 av = *(const float4*)&A[(size_t)(mb + am) * lda + k0 + ak];
        As[ak + 0][am] = av.x;
        As[ak + 1][am] = av.y;
        As[ak + 2][am] = av.z;
        As[ak + 3][am] = av.w;
        #pragma unroll
        for (int i = 0; i < BK / WKSTEP; ++i) {
            int kw = wk0 + i * WKSTEP;
            Ws[kw][wn] = (nb + wn < N) ? Wk[(size_t)(k0 + kw) * ldw + nb + wn] : 0.f;
        }
        __syncthreads();
        #pragma unroll
        for (int k = 0; k < BK; ++k) {
            float a[TM], w[TN];
            #pragma unroll
            for (int i = 0; i < TM; ++i) a[i] = As[k][ty * TM + i];
            #pragma unroll
            for (int j = 0; j < TN; ++j) w[j] = Ws[k][tx * TN + j];
            #pragma unroll
            for (int i = 0; i < TM; ++i)
                #pragma unroll
                for (int j = 0; j < TN; ++j)
                    acc[i][j] = fmaf(a[i], w[j], acc[i][j]);
        }
        __syncthreads();
    }

    #pragma unroll
    for (int i = 0; i < TM; ++i) {
        int m = mb + ty * TM + i;
        #pragma unroll
        for (int j = 0; j < TN; ++j) {
            int n = nb + tx * TN + j;
            if (n < N) {
                float v = acc[i][j];
                if (bias) v += bias[n];
                if (ACT1 == 1) v = tanh_f(v);
                if (OUTBF) ((ushort_t*)Cv)[(size_t)m * ldc + n] = f2bf(v);
                else       ((float*)Cv)[(size_t)m * ldc + n] = v;
            }
        }
    }
}

// ---------------------------------------------------------------------------
// MFMA bf16 split GEMM: C[M,N] = act( A @ B^T + bias )
// A rows [M][lda] bf16 hi(/lo); B transposed [N][ldb] bf16 hi(/lo).
// Split-3 when BLO: Ahi*Bhi + Alo*Bhi + Ahi*Blo.
// Wave = NT col-tiles of 16 x MT row-tiles of 16. 4 waves along N per block.
// PERM: C row m = t*128+b -> C + (m&127)*ldc + (m>>7)*ldc2 + n.
// ---------------------------------------------------------------------------
template<int MT, int NT, int ACT1, int ACT2, bool BLO, bool OUTBF, bool PERM>
__global__ __launch_bounds__(256)
void mgemm_k(const ushort_t* __restrict__ Ahi, const ushort_t* __restrict__ Alo, int lda,
             const ushort_t* __restrict__ Bhi, const ushort_t* __restrict__ Blo, int ldb,
             const float* __restrict__ bias, const float* __restrict__ bias2, int N1,
             void* __restrict__ Cv, long long ldc, long long ldc2, int N, int K)
{
    const int wv = threadIdx.x >> 6, lane = threadIdx.x & 63;
    const int n0 = (blockIdx.x * 4 + wv) * (16 * NT);
    if (n0 >= N) return;
    const int m0 = blockIdx.y * (MT * 16);
    const int col = lane & 15, kq = (lane >> 4) * 8;

    const ushort_t* bh[NT];
    const ushort_t* bl[NT];
    #pragma unroll
    for (int ct = 0; ct < NT; ++ct) {
        bh[ct] = Bhi + (size_t)(n0 + ct * 16 + col) * ldb + kq;
        bl[ct] = BLO ? (Blo + (size_t)(n0 + ct * 16 + col) * ldb + kq) : nullptr;
    }
    const ushort_t* ah[MT];
    const ushort_t* al[MT];
    #pragma unroll
    for (int mt = 0; mt < MT; ++mt) {
        size_t off = (size_t)(m0 + mt * 16 + col) * lda + kq;
        ah[mt] = Ahi + off;
        al[mt] = Alo + off;
    }

    f32x4 acc[NT][MT];
    #pragma unroll
    for (int ct = 0; ct < NT; ++ct)
        #pragma unroll
        for (int mt = 0; mt < MT; ++mt) acc[ct][mt] = (f32x4){0.f, 0.f, 0.f, 0.f};

    for (int k0 = 0; k0 < K; k0 += 32) {
        bf16x8 Bh[NT], Bl[NT];
        #pragma unroll
        for (int ct = 0; ct < NT; ++ct) {
            Bh[ct] = *(const bf16x8*)bh[ct]; bh[ct] += 32;
            if (BLO) { Bl[ct] = *(const bf16x8*)bl[ct]; bl[ct] += 32; }
        }
        #pragma unroll
        for (int mt = 0; mt < MT; ++mt) {
            bf16x8 afh = *(const bf16x8*)ah[mt]; ah[mt] += 32;
            bf16x8 afl = *(const bf16x8*)al[mt]; al[mt] += 32;
            #pragma unroll
            for (int ct = 0; ct < NT; ++ct) {
                acc[ct][mt] = __builtin_amdgcn_mfma_f32_16x16x32_bf16(afh, Bh[ct], acc[ct][mt], 0, 0, 0);
                acc[ct][mt] = __builtin_amdgcn_mfma_f32_16x16x32_bf16(afl, Bh[ct], acc[ct][mt], 0, 0, 0);
                if (BLO)
                    acc[ct][mt] = __builtin_amdgcn_mfma_f32_16x16x32_bf16(afh, Bl[ct], acc[ct][mt], 0, 0, 0);
            }
        }
    }

    #pragma unroll
    for (int ct = 0; ct < NT; ++ct) {
        const int nc = n0 + ct * 16 + col;
        if (nc >= N) continue;
        const bool ns = ((n0 + ct * 16) >= N1);
        float bv = ns ? (bias2 ? bias2[nc - N1] : 0.f) : (bias ? bias[nc] : 0.f);
        const int act = ns ? ACT2 : ACT1;
        #pragma unroll
        for (int mt = 0; mt < MT; ++mt)
            #pragma unroll
            for (int r = 0; r < 4; ++r) {
                int row = m0 + mt * 16 + (lane >> 4) * 4 + r;
                float v = acc[ct][mt][r] + bv;
                if (act == 1)      v = tanh_f(v);
                else if (act == 2) v = sigm_f(v);
                size_t off = PERM ? ((size_t)(row & 127) * ldc + (size_t)(row >> 7) * ldc2 + nc)
                                  : ((size_t)row * ldc + nc);
                if (OUTBF) ((ushort_t*)Cv)[off] = f2bf(v);
                else       ((float*)Cv)[off] = v;
            }
    }
}

// ---------------------------------------------------------------------------
// Transpose + convert: W[K][N] fp32 -> Thi/Tlo [N][ldt] bf16 at col offset kofs
// ---------------------------------------------------------------------------
template<bool LO>
__global__ __launch_bounds__(256)
void convT_k(const float* __restrict__ W, int K, int N,
             ushort_t* __restrict__ Thi, ushort_t* __restrict__ Tlo,
             int ldt, int kofs)
{
    __shared__ float tile[64][65];
    int n0 = blockIdx.x * 64, k0 = blockIdx.y * 64;
    int c = threadIdx.x & 63, r0 = threadIdx.x >> 6;
    #pragma unroll
    for (int i = 0; i < 16; ++i) {
        int r = r0 * 16 + i;
        tile[r][c] = (n0 + c < N) ? W[(size_t)(k0 + r) * N + n0 + c] : 0.f;
    }
    __syncthreads();
    int nr = threadIdx.x >> 2, kc = (threadIdx.x & 3) * 16;
    if (n0 + nr < N) {
        ushort_t* ph = Thi + (size_t)(n0 + nr) * ldt + kofs + k0 + kc;
        ushort_t* pl = LO ? (Tlo + (size_t)(n0 + nr) * ldt + kofs + k0 + kc) : nullptr;
        #pragma unroll
        for (int j = 0; j < 16; ++j) {
            float v = tile[kc + j][nr];
            ushort_t h = f2bf(v);
            ph[j] = h;
            if (LO) pl[j] = f2bf(v - bf2f(h));
        }
    }
}

// elementwise fp32 -> bf16 (hi only)
__global__ void convbf_k(const float* __restrict__ src, ushort_t* __restrict__ dst,
                         long long n)
{
    long long i = (long long)(blockIdx.x * 256 + threadIdx.x) * 4;
    long long stride = (long long)gridDim.x * 1024;
    for (; i + 3 < n; i += stride) {
        float4 v = *(const float4*)&src[i];
        dst[i + 0] = f2bf(v.x); dst[i + 1] = f2bf(v.y);
        dst[i + 2] = f2bf(v.z); dst[i + 3] = f2bf(v.w);
    }
}

// elementwise fp32 -> bf16 hi + lo
__global__ void convbf2_k(const float* __restrict__ src, ushort_t* __restrict__ hi,
                          ushort_t* __restrict__ lo, long long n)
{
    long long i = (long long)(blockIdx.x * 256 + threadIdx.x) * 4;
    long long stride = (long long)gridDim.x * 1024;
    for (; i + 3 < n; i += stride) {
        float4 v = *(const float4*)&src[i];
        float vs[4] = {v.x, v.y, v.z, v.w};
        #pragma unroll
        for (int j = 0; j < 4; ++j) {
            ushort_t h = f2bf(vs[j]);
            hi[i + j] = h;
            lo[i + j] = f2bf(vs[j] - bf2f(h));
        }
    }
}

// feat_mean
__global__ __launch_bounds__(256)
void featmean_k(const float* __restrict__ img, float* __restrict__ fm)
{
    int b = blockIdx.x, tid = threadIdx.x;
    const float* base = img + (size_t)b * Ll * ENCe;
    for (int e = tid; e < ENCe; e += 256) {
        float s = 0.f;
        for (int l = 0; l < Ll; ++l) s += base[l * ENCe + e];
        fm[b * ENCe + e] = s * (1.f / (float)Ll);
    }
}

__global__ void bcomb_k(const float* __restrict__ bih, const float* __restrict__ bhh,
                        float* __restrict__ bc)
{
    int i = blockIdx.x * 256 + threadIdx.x;
    if (i < 4 * Hh) bc[i] = bih[i] + bhh[i];
}

// h0 fp32 -> xh hi/lo at col 768
__global__ void hconv_k(const float* __restrict__ h, ushort_t* __restrict__ xhi,
                        ushort_t* __restrict__ xlo)
{
    int i = blockIdx.x * 256 + threadIdx.x;
    if (i >= Bb * Hh) return;
    int b = i / Hh, j = i % Hh;
    float v = h[i];
    ushort_t hb = f2bf(v);
    xhi[b * 1280 + 768 + j] = hb;
    xlo[b * 1280 + 768 + j] = f2bf(v - bf2f(hb));
}

// ---------------------------------------------------------------------------
// Fused attention: per block b (512 threads = 8 waves):
//  score (tanh dot) -> softmax -> alphas out -> emb x[0:256] -> ctx*gate x[256:768]
// ---------------------------------------------------------------------------
template<bool IMGBF>
__global__ __launch_bounds__(512)
void attn_fused_k(const ushort_t* __restrict__ enc, const float* __restrict__ dgb,
                  const float* __restrict__ v_att,
                  const ushort_t* __restrict__ img_bf, const float* __restrict__ img_f,
                  const float* __restrict__ emb, const int* __restrict__ captions,
                  float* __restrict__ alphas, long long alpha_stride,
                  ushort_t* __restrict__ xhi, ushort_t* __restrict__ xlo, int t)
{
    int b = blockIdx.x, tid = threadIdx.x;
    __shared__ float dp[Hh], va[Hh], es[Ll], red[8];

    if (tid < Hh) {
        dp[tid] = dgb[b * 1024 + tid];
        va[tid] = v_att[tid];
    }
    __syncthreads();

    int wv = tid >> 6, ln = tid & 63;
    const ushort_t* ep = enc + (size_t)b * Ll * Hh;
    for (int l = wv; l < Ll; l += 8) {
        const ushort_t* row = ep + (size_t)l * Hh;
        float s = 0.f;
        #pragma unroll
        for (int r = 0; r < 8; ++r) {
            int k = r * 64 + ln;
            s += tanh_f(bf2f(row[k]) + dp[k]) * va[k];
        }
        #pragma unroll
        for (int o = 32; o; o >>= 1) s += __shfl_xor(s, o);
        if (ln == 0) es[l] = s;
    }
    __syncthreads();

    // softmax over es[0..195]
    float v = (tid < Ll) ? es[tid] : -1e30f;
    float m = v;
    #pragma unroll
    for (int o = 32; o; o >>= 1) m = fmaxf(m, __shfl_xor(m, o));
    if (ln == 0) red[wv] = m;
    __syncthreads();
    m = red[0];
    #pragma unroll
    for (int i = 1; i < 8; ++i) m = fmaxf(m, red[i]);
    __syncthreads();
    float p = (tid < Ll) ? __expf(v - m) : 0.f;
    float s = p;
    #pragma unroll
    for (int o = 32; o; o >>= 1) s += __shfl_xor(s, o);
    if (ln == 0) red[wv] = s;
    __syncthreads();
    s = 0.f;
    #pragma unroll
    for (int i = 0; i < 8; ++i) s += red[i];
    float inv = 1.f / s;
    if (tid < Ll) {
        float a = p * inv;
        es[tid] = a;
        alphas[(size_t)b * alpha_stride + tid] = a;
    }
    // fused: x[b][0:256] = emb[captions[b,t]]
    if (tid < Ee) {
        float xv = emb[(size_t)captions[b * Tt + t] * Ee + tid];
        ushort_t hb = f2bf(xv);
        xhi[b * 1280 + tid] = hb;
        xlo[b * 1280 + tid] = f2bf(xv - bf2f(hb));
    }
    __syncthreads();

    // context (one e-column per thread, 512 == ENCe)
    int e = tid;
    float acc = 0.f;
    if (IMGBF) {
        const ushort_t* ib = img_bf + (size_t)b * Ll * ENCe + e;
        #pragma unroll 4
        for (int l = 0; l < Ll; ++l) acc = fmaf(es[l], bf2f(ib[(size_t)l * ENCe]), acc);
    } else {
        const float* ib = img_f + (size_t)b * Ll * ENCe + e;
        #pragma unroll 4
        for (int l = 0; l < Ll; ++l) acc = fmaf(es[l], ib[(size_t)l * ENCe], acc);
    }
    float xv = acc * dgb[b * 1024 + 512 + e];
    ushort_t hb = f2bf(xv);
    int j = Ee + e;
    xhi[b * 1280 + j] = hb;
    xlo[b * 1280 + j] = f2bf(xv - bf2f(hb));
}

// LSTM elementwise; writes c, h->xh (hi/lo) and h->hseq[t] (hi/lo)
__global__ void lstm_k(const float* __restrict__ gates, float* __restrict__ c,
                       ushort_t* __restrict__ xhi, ushort_t* __restrict__ xlo,
                       ushort_t* __restrict__ hseqH, ushort_t* __restrict__ hseqL, int t)
{
    int i = blockIdx.x * 256 + threadIdx.x;
    if (i >= Bb * Hh) return;
    int b = i / Hh, j = i % Hh;
    const float* g = gates + (size_t)b * 4 * Hh;
    float ig = sigm_f(g[j]);
    float fg = sigm_f(g[Hh + j]);
    float gg = tanh_f(g[2 * Hh + j]);
    float og = sigm_f(g[3 * Hh + j]);
    float cn = fg * c[i] + ig * gg;
    c[i] = cn;
    float hv = og * tanh_f(cn);
    ushort_t hb = f2bf(hv);
    ushort_t lb = f2bf(hv - bf2f(hb));
    xhi[b * 1280 + 768 + j] = hb;
    xlo[b * 1280 + 768 + j] = lb;
    size_t o = ((size_t)t * Bb + b) * Hh + j;
    hseqH[o] = hb;
    hseqL[o] = lb;
}

// ---------------------------------------------------------------------------
extern "C" void kernel_launch(void* const* d_in, const int* in_sizes, int n_in,
                              void* d_out, int out_size, void* d_ws, size_t ws_size,
                              hipStream_t stream)
{
    const float* img    = (const float*)d_in[0];
    const float* W_h    = (const float*)d_in[1];
    const float* b_h    = (const float*)d_in[2];
    const float* W_c    = (const float*)d_in[3];
    const float* b_c    = (const float*)d_in[4];
    const float* W_gate = (const float*)d_in[5];
    const float* b_gate = (const float*)d_in[6];
    const float* emb    = (const float*)d_in[7];
    const float* W_ae   = (const float*)d_in[8];
    const float* b_ae   = (const float*)d_in[9];
    const float* W_ad   = (const float*)d_in[10];
    const float* b_ad   = (const float*)d_in[11];
    const float* v_att  = (const float*)d_in[12];
    const float* W_ih   = (const float*)d_in[14];
    const float* b_ih   = (const float*)d_in[15];
    const float* W_hh   = (const float*)d_in[16];
    const float* b_hh   = (const float*)d_in[17];
    const float* W_out  = (const float*)d_in[18];
    const float* b_out  = (const float*)d_in[19];
    const int* captions = (const int*)d_in[20];

    float* out    = (float*)d_out;                       // [B,T,V]
    float* alphas = out + (size_t)Bb * Tt * Vv;          // [B,T,L]

    // ---- workspace allocator (256B aligned) ----
    char* p = (char*)d_ws;
    auto alloc = [&](size_t bytes) -> char* {
        char* r = p; p += (bytes + 255) & ~(size_t)255; return r;
    };
    const size_t szEnc   = (size_t)Bb * Ll * Hh * 2;      // 25.7 MB
    const size_t szWout  = (size_t)Vv * Hh * 2;           // 10.24 MB
    const size_t szWg    = (size_t)(4 * Hh) * 1280 * 2;   // 5.24 MB
    const size_t szWdg   = (size_t)1024 * Hh * 2;         // 1.05 MB
    const size_t szWae   = (size_t)Hh * Hh * 2;           // 0.52 MB
    const size_t szXh    = (size_t)Bb * 1280 * 2;         // 0.33 MB
    const size_t szHseq  = (size_t)Tt * Bb * Hh * 2;      // 2.62 MB
    const size_t szImg   = (size_t)Bb * Ll * ENCe * 2;    // 25.7 MB

    ushort_t* enc_hi = (ushort_t*)alloc(szEnc);
    ushort_t* WoutH  = (ushort_t*)alloc(szWout);
    ushort_t* WgH    = (ushort_t*)alloc(szWg);
    ushort_t* WdgH   = (ushort_t*)alloc(szWdg);
    ushort_t* WaeTH  = (ushort_t*)alloc(szWae);
    ushort_t* WaeTL  = (ushort_t*)alloc(szWae);
    ushort_t* xhH    = (ushort_t*)alloc(szXh);
    ushort_t* xhL    = (ushort_t*)alloc(szXh);
    ushort_t* hseqH  = (ushort_t*)alloc(szHseq);
    ushort_t* hseqL  = (ushort_t*)alloc(szHseq);
    float*    cbuf   = (float*)alloc((size_t)Bb * Hh * 4);
    float*    dgb    = (float*)alloc((size_t)Bb * 1024 * 4);
    float*    S      = (float*)alloc((size_t)Bb * 2048 * 4); // gates / fm+h0 union
    float*    bcomb  = (float*)alloc(4 * Hh * 4);

    auto tryAlloc = [&](size_t bytes) -> char* {
        size_t used = (size_t)(p - (char*)d_ws);
        size_t rounded = (bytes + 255) & ~(size_t)255;
        if (used + rounded > ws_size) return nullptr;
        return alloc(bytes);
    };
    ushort_t* WoutL = (ushort_t*)tryAlloc(szWout);
    ushort_t* WgL   = (ushort_t*)tryAlloc(szWg);
    ushort_t* WdgL  = (ushort_t*)tryAlloc(szWdg);
    ushort_t* imgH  = (ushort_t*)tryAlloc(szImg);
    ushort_t* imgL  = (ushort_t*)tryAlloc(szImg);

    float* fm  = S;                      // [B][512]
    float* h0b = S + Bb * ENCe;          // [B][512]
    float* gates = S;                    // [B][2048] (after h0 consumed)

    dim3 blk(256);
    const int NOSPLIT = 0x40000000;

    // ---- one-time weight conversion (transposed bf16 hi/lo) ----
    if (WoutL) convT_k<true ><<<dim3(157, 8), blk, 0, stream>>>(W_out, Hh, Vv, WoutH, WoutL, Hh, 0);
    else       convT_k<false><<<dim3(157, 8), blk, 0, stream>>>(W_out, Hh, Vv, WoutH, nullptr, Hh, 0);
    if (WgL) {
        convT_k<true ><<<dim3(32, 12), blk, 0, stream>>>(W_ih, 768, 2048, WgH, WgL, 1280, 0);
        convT_k<true ><<<dim3(32, 8),  blk, 0, stream>>>(W_hh, Hh,  2048, WgH, WgL, 1280, 768);
    } else {
        convT_k<false><<<dim3(32, 12), blk, 0, stream>>>(W_ih, 768, 2048, WgH, nullptr, 1280, 0);
        convT_k<false><<<dim3(32, 8),  blk, 0, stream>>>(W_hh, Hh,  2048, WgH, nullptr, 1280, 768);
    }
    if (WdgL) {
        convT_k<true ><<<dim3(8, 8), blk, 0, stream>>>(W_ad,   Hh, Hh, WdgH, WdgL, Hh, 0);
        convT_k<true ><<<dim3(8, 8), blk, 0, stream>>>(W_gate, Hh, ENCe, WdgH + (size_t)512 * Hh,
                                                       WdgL + (size_t)512 * Hh, Hh, 0);
    } else {
        convT_k<false><<<dim3(8, 8), blk, 0, stream>>>(W_ad,   Hh, Hh, WdgH, nullptr, Hh, 0);
        convT_k<false><<<dim3(8, 8), blk, 0, stream>>>(W_gate, Hh, ENCe, WdgH + (size_t)512 * Hh,
                                                       nullptr, Hh, 0);
    }

    bcomb_k<<<(4 * Hh + 255) / 256, blk, 0, stream>>>(b_ih, b_hh, bcomb);
    featmean_k<<<Bb, blk, 0, stream>>>(img, fm);

    // h0 = tanh(fm @ W_h + b_h) ; c0 = tanh(fm @ W_c + b_c)
    gemm_k<32, 2, 4, 1, 0><<<dim3(Hh / 32, Bb / 64), blk, 0, stream>>>(
        fm, ENCe, W_h, Hh, b_h, h0b, Hh, Bb, Hh, ENCe);
    gemm_k<32, 2, 4, 1, 0><<<dim3(Hh / 32, Bb / 64), blk, 0, stream>>>(
        fm, ENCe, W_c, Hh, b_c, cbuf, Hh, Bb, Hh, ENCe);
    hconv_k<<<(Bb * Hh + 255) / 256, blk, 0, stream>>>(h0b, xhH, xhL);

    // enc_proj = img @ W_ae + b_ae -> bf16
    if (imgL) {
        convbf2_k<<<2048, blk, 0, stream>>>(img, imgH, imgL, (long long)Bb * Ll * ENCe);
        convT_k<true><<<dim3(8, 8), blk, 0, stream>>>(W_ae, Hh, Hh, WaeTH, WaeTL, Hh, 0);
        mgemm_k<8, 2, 0, 0, true, true, false><<<dim3(4, 196), blk, 0, stream>>>(
            imgH, imgL, ENCe, WaeTH, WaeTL, Hh, b_ae, nullptr, NOSPLIT,
            enc_hi, Hh, 0, Hh, ENCe);
    } else {
        if (imgH) convbf_k<<<2048, blk, 0, stream>>>(img, imgH, (long long)Bb * Ll * ENCe);
        gemm_k<64, 4, 4, 0, 1><<<dim3(Hh / 64, (Bb * Ll) / 64), blk, 0, stream>>>(
            img, ENCe, W_ae, Hh, b_ae, enc_hi, Hh, Bb * Ll, Hh, ENCe);
    }

    const ushort_t* hH = xhH + 768;  // h rows inside xh, lda=1280
    const ushort_t* hL = xhL + 768;

    for (int t = 0; t < Tt; ++t) {
        // dg = [h@W_ad + b_ad | sigmoid(h@W_gate + b_gate)]
        if (WdgL)
            mgemm_k<1, 1, 0, 2, true , false, false><<<dim3(16, 8), blk, 0, stream>>>(
                hH, hL, 1280, WdgH, WdgL, Hh, b_ad, b_gate, 512, dgb, 1024, 0, 1024, Hh);
        else
            mgemm_k<1, 1, 0, 2, false, false, false><<<dim3(16, 8), blk, 0, stream>>>(
                hH, hL, 1280, WdgH, nullptr, Hh, b_ad, b_gate, 512, dgb, 1024, 0, 1024, Hh);

        if (imgH)
            attn_fused_k<true ><<<Bb, dim3(512), 0, stream>>>(
                enc_hi, dgb, v_att, imgH, nullptr, emb, captions,
                alphas + (size_t)t * Ll, (long long)Tt * Ll, xhH, xhL, t);
        else
            attn_fused_k<false><<<Bb, dim3(512), 0, stream>>>(
                enc_hi, dgb, v_att, nullptr, img, emb, captions,
                alphas + (size_t)t * Ll, (long long)Tt * Ll, xhH, xhL, t);

        // gates = [x|h] @ [W_ih;W_hh]^T + bcomb
        if (WgL)
            mgemm_k<2, 1, 0, 0, true , false, false><<<dim3(32, 4), blk, 0, stream>>>(
                xhH, xhL, 1280, WgH, WgL, 1280, bcomb, nullptr, NOSPLIT,
                gates, 2048, 0, 2048, 1280);
        else
            mgemm_k<2, 1, 0, 0, false, false, false><<<dim3(32, 4), blk, 0, stream>>>(
                xhH, xhL, 1280, WgH, nullptr, 1280, bcomb, nullptr, NOSPLIT,
                gates, 2048, 0, 2048, 1280);

        lstm_k<<<(Bb * Hh + 255) / 256, blk, 0, stream>>>(gates, cbuf, xhH, xhL,
                                                          hseqH, hseqL, t);
    }

    // Batched logits: [T*B, V] = hseq @ Wout^T + b_out, permuted into out[b][t][v]
    if (WoutL)
        mgemm_k<8, 2, 0, 0, true , false, true><<<dim3(79, 20), blk, 0, stream>>>(
            hseqH, hseqL, Hh, WoutH, WoutL, Hh, b_out, nullptr, NOSPLIT,
            out, (long long)Tt * Vv, (long long)Vv, Vv, Hh);
    else
        mgemm_k<8, 2, 0, 0, false, false, true><<<dim3(79, 20), blk, 0, stream>>>(
            hseqH, hseqL, Hh, WoutH, nullptr, Hh, b_out, nullptr, NOSPLIT,
            out, (long long)Tt * Vv, (long long)Vv, Vv, Hh);
}

// Round 4
// 1997.491 us; speedup vs baseline: 2.4748x; 1.1703x over previous
//
#include <hip/hip_runtime.h>
#include <math.h>

typedef unsigned short ushort_t;
typedef __attribute__((ext_vector_type(8))) short bf16x8;
typedef __attribute__((ext_vector_type(4))) float f32x4;

constexpr int Bb  = 128;
constexpr int Ll  = 196;
constexpr int ENCe= 512;
constexpr int Hh  = 512;
constexpr int Ee  = 256;
constexpr int Vv  = 10000;
constexpr int Tt  = 20;

#define DEV __device__ __forceinline__

DEV float sigm_f(float x) { return 1.f / (1.f + __expf(-x)); }
DEV float tanh_f(float x) {
    x = fminf(fmaxf(x, -15.f), 15.f);
    float e = __expf(2.f * x);
    return (e - 1.f) / (e + 1.f);
}
DEV ushort_t f2bf(float v) {
    unsigned u = __float_as_uint(v);
    return (ushort_t)((u + 0x7FFFu + ((u >> 16) & 1u)) >> 16);
}
DEV float bf2f(ushort_t h) { return __uint_as_float(((unsigned)h) << 16); }

// ---------------------------------------------------------------------------
// fp32 tiled GEMM (h0/c0 + enc_proj fallback). OUTBF emits bf16.
// ---------------------------------------------------------------------------
template<int BN, int TM, int TN, int ACT1, int OUTBF>
__global__ __launch_bounds__(256)
void gemm_k(const float* __restrict__ A, int lda,
            const float* __restrict__ Wk, int ldw,
            const float* __restrict__ bias,
            void* __restrict__ Cv, long long ldc,
            int M, int N, int K)
{
    constexpr int BM = 64, BK = 16;
    constexpr int TX = BN / TN, TY = BM / TM;
    static_assert(TX * TY == 256, "bad tile config");
    __shared__ float As[BK][BM];
    __shared__ float Ws[BK][BN];

    const int tid = threadIdx.x;
    const int tx = tid % TX, ty = tid / TX;
    const int nb = blockIdx.x * BN, mb = blockIdx.y * BM;

    float acc[TM][TN] = {};
    const int am = tid >> 2;
    const int ak = (tid & 3) * 4;
    const int wn = tid % BN;
    const int wk0 = tid / BN;
    constexpr int WKSTEP = 256 / BN;

    for (int k0 = 0; k0 < K; k0 += BK) {
        float4 av = *(const float4*)&A[(size_t)(mb + am) * lda + k0 + ak];
        As[ak + 0][am] = av.x;
        As[ak + 1][am] = av.y;
        As[ak + 2][am] = av.z;
        As[ak + 3][am] = av.w;
        #pragma unroll
        for (int i = 0; i < BK / WKSTEP; ++i) {
            int kw = wk0 + i * WKSTEP;
            Ws[kw][wn] = (nb + wn < N) ? Wk[(size_t)(k0 + kw) * ldw + nb + wn] : 0.f;
        }
        __syncthreads();
        #pragma unroll
        for (int k = 0; k < BK; ++k) {
            float a[TM], w[TN];
            #pragma unroll
            for (int i = 0; i < TM; ++i) a[i] = As[k][ty * TM + i];
            #pragma unroll
            for (int j = 0; j < TN; ++j) w[j] = Ws[k][tx * TN + j];
            #pragma unroll
            for (int i = 0; i < TM; ++i)
                #pragma unroll
                for (int j = 0; j < TN; ++j)
                    acc[i][j] = fmaf(a[i], w[j], acc[i][j]);
        }
        __syncthreads();
    }

    #pragma unroll
    for (int i = 0; i < TM; ++i) {
        int m = mb + ty * TM + i;
        #pragma unroll
        for (int j = 0; j < TN; ++j) {
            int n = nb + tx * TN + j;
            if (n < N) {
                float v = acc[i][j];
                if (bias) v += bias[n];
                if (ACT1 == 1) v = tanh_f(v);
                if (OUTBF) ((ushort_t*)Cv)[(size_t)m * ldc + n] = f2bf(v);
                else       ((float*)Cv)[(size_t)m * ldc + n] = v;
            }
        }
    }
}

// ---------------------------------------------------------------------------
// MFMA bf16 split GEMM: C[M,N] = act( A @ B^T + bias )
// A rows [M][lda] bf16 hi(/lo); B transposed [N][ldb] bf16 hi(/lo).
// Split-3 when BLO: Ahi*Bhi + Alo*Bhi + Ahi*Blo.
// Wave = NT col-tiles of 16 x MT row-tiles of 16. 4 waves along N per block.
// PERM: C row m = t*128+b -> C + (m&127)*ldc + (m>>7)*ldc2 + n  (nontemporal).
// XSWZ: 1D grid = nstrips*mblks; bijective XCD swizzle so consecutive linear
//       ids (same XCD) iterate m-blocks within one n-strip (B reuse in L2).
// ---------------------------------------------------------------------------
template<int MT, int NT, int ACT1, int ACT2, bool BLO, bool OUTBF, bool PERM, bool XSWZ>
__global__ __launch_bounds__(256)
void mgemm_k(const ushort_t* __restrict__ Ahi, const ushort_t* __restrict__ Alo, int lda,
             const ushort_t* __restrict__ Bhi, const ushort_t* __restrict__ Blo, int ldb,
             const float* __restrict__ bias, const float* __restrict__ bias2, int N1,
             void* __restrict__ Cv, long long ldc, long long ldc2, int N, int K,
             int mblks)
{
    int bx, by;
    if (XSWZ) {
        int nwg = gridDim.x;
        int orig = blockIdx.x;
        int xcd = orig & 7, idx = orig >> 3;
        int q = nwg >> 3, r = nwg & 7;
        int lin = (xcd < r ? xcd * (q + 1) : r * (q + 1) + (xcd - r) * q) + idx;
        bx = lin / mblks;
        by = lin - bx * mblks;
    } else {
        bx = blockIdx.x; by = blockIdx.y;
    }

    const int wv = threadIdx.x >> 6, lane = threadIdx.x & 63;
    const int n0 = (bx * 4 + wv) * (16 * NT);
    if (n0 >= N) return;
    const int m0 = by * (MT * 16);
    const int col = lane & 15, kq = (lane >> 4) * 8;

    const ushort_t* bh[NT];
    const ushort_t* bl[NT];
    #pragma unroll
    for (int ct = 0; ct < NT; ++ct) {
        bh[ct] = Bhi + (size_t)(n0 + ct * 16 + col) * ldb + kq;
        bl[ct] = BLO ? (Blo + (size_t)(n0 + ct * 16 + col) * ldb + kq) : nullptr;
    }
    const ushort_t* ah[MT];
    const ushort_t* al[MT];
    #pragma unroll
    for (int mt = 0; mt < MT; ++mt) {
        size_t off = (size_t)(m0 + mt * 16 + col) * lda + kq;
        ah[mt] = Ahi + off;
        al[mt] = Alo + off;
    }

    f32x4 acc[NT][MT];
    #pragma unroll
    for (int ct = 0; ct < NT; ++ct)
        #pragma unroll
        for (int mt = 0; mt < MT; ++mt) acc[ct][mt] = (f32x4){0.f, 0.f, 0.f, 0.f};

    for (int k0 = 0; k0 < K; k0 += 32) {
        bf16x8 Bh[NT], Bl[NT];
        #pragma unroll
        for (int ct = 0; ct < NT; ++ct) {
            Bh[ct] = *(const bf16x8*)bh[ct]; bh[ct] += 32;
            if (BLO) { Bl[ct] = *(const bf16x8*)bl[ct]; bl[ct] += 32; }
        }
        #pragma unroll
        for (int mt = 0; mt < MT; ++mt) {
            bf16x8 afh = *(const bf16x8*)ah[mt]; ah[mt] += 32;
            bf16x8 afl = *(const bf16x8*)al[mt]; al[mt] += 32;
            #pragma unroll
            for (int ct = 0; ct < NT; ++ct) {
                acc[ct][mt] = __builtin_amdgcn_mfma_f32_16x16x32_bf16(afh, Bh[ct], acc[ct][mt], 0, 0, 0);
                acc[ct][mt] = __builtin_amdgcn_mfma_f32_16x16x32_bf16(afl, Bh[ct], acc[ct][mt], 0, 0, 0);
                if (BLO)
                    acc[ct][mt] = __builtin_amdgcn_mfma_f32_16x16x32_bf16(afh, Bl[ct], acc[ct][mt], 0, 0, 0);
            }
        }
    }

    #pragma unroll
    for (int ct = 0; ct < NT; ++ct) {
        const int nc = n0 + ct * 16 + col;
        if (nc >= N) continue;
        const bool ns = ((n0 + ct * 16) >= N1);
        float bv = ns ? (bias2 ? bias2[nc - N1] : 0.f) : (bias ? bias[nc] : 0.f);
        const int act = ns ? ACT2 : ACT1;
        #pragma unroll
        for (int mt = 0; mt < MT; ++mt)
            #pragma unroll
            for (int r = 0; r < 4; ++r) {
                int row = m0 + mt * 16 + (lane >> 4) * 4 + r;
                float v = acc[ct][mt][r] + bv;
                if (act == 1)      v = tanh_f(v);
                else if (act == 2) v = sigm_f(v);
                size_t off = PERM ? ((size_t)(row & 127) * ldc + (size_t)(row >> 7) * ldc2 + nc)
                                  : ((size_t)row * ldc + nc);
                if (OUTBF)      ((ushort_t*)Cv)[off] = f2bf(v);
                else if (PERM)  __builtin_nontemporal_store(v, &((float*)Cv)[off]);
                else            ((float*)Cv)[off] = v;
            }
    }
}

// ---------------------------------------------------------------------------
// Transpose + convert: W[K][N] fp32 -> Thi/Tlo [N][ldt] bf16 at col offset kofs
// ---------------------------------------------------------------------------
template<bool LO>
__global__ __launch_bounds__(256)
void convT_k(const float* __restrict__ W, int K, int N,
             ushort_t* __restrict__ Thi, ushort_t* __restrict__ Tlo,
             int ldt, int kofs)
{
    __shared__ float tile[64][65];
    int n0 = blockIdx.x * 64, k0 = blockIdx.y * 64;
    int c = threadIdx.x & 63, r0 = threadIdx.x >> 6;
    #pragma unroll
    for (int i = 0; i < 16; ++i) {
        int r = r0 * 16 + i;
        tile[r][c] = (n0 + c < N) ? W[(size_t)(k0 + r) * N + n0 + c] : 0.f;
    }
    __syncthreads();
    int nr = threadIdx.x >> 2, kc = (threadIdx.x & 3) * 16;
    if (n0 + nr < N) {
        ushort_t* ph = Thi + (size_t)(n0 + nr) * ldt + kofs + k0 + kc;
        ushort_t* pl = LO ? (Tlo + (size_t)(n0 + nr) * ldt + kofs + k0 + kc) : nullptr;
        #pragma unroll
        for (int j = 0; j < 16; ++j) {
            float v = tile[kc + j][nr];
            ushort_t h = f2bf(v);
            ph[j] = h;
            if (LO) pl[j] = f2bf(v - bf2f(h));
        }
    }
}

// elementwise fp32 -> bf16 (hi only)
__global__ void convbf_k(const float* __restrict__ src, ushort_t* __restrict__ dst,
                         long long n)
{
    long long i = (long long)(blockIdx.x * 256 + threadIdx.x) * 4;
    long long stride = (long long)gridDim.x * 1024;
    for (; i + 3 < n; i += stride) {
        float4 v = *(const float4*)&src[i];
        dst[i + 0] = f2bf(v.x); dst[i + 1] = f2bf(v.y);
        dst[i + 2] = f2bf(v.z); dst[i + 3] = f2bf(v.w);
    }
}

// elementwise fp32 -> bf16 hi + lo
__global__ void convbf2_k(const float* __restrict__ src, ushort_t* __restrict__ hi,
                          ushort_t* __restrict__ lo, long long n)
{
    long long i = (long long)(blockIdx.x * 256 + threadIdx.x) * 4;
    long long stride = (long long)gridDim.x * 1024;
    for (; i + 3 < n; i += stride) {
        float4 v = *(const float4*)&src[i];
        float vs[4] = {v.x, v.y, v.z, v.w};
        #pragma unroll
        for (int j = 0; j < 4; ++j) {
            ushort_t h = f2bf(vs[j]);
            hi[i + j] = h;
            lo[i + j] = f2bf(vs[j] - bf2f(h));
        }
    }
}

// feat_mean
__global__ __launch_bounds__(256)
void featmean_k(const float* __restrict__ img, float* __restrict__ fm)
{
    int b = blockIdx.x, tid = threadIdx.x;
    const float* base = img + (size_t)b * Ll * ENCe;
    for (int e = tid; e < ENCe; e += 256) {
        float s = 0.f;
        for (int l = 0; l < Ll; ++l) s += base[l * ENCe + e];
        fm[b * ENCe + e] = s * (1.f / (float)Ll);
    }
}

__global__ void bcomb_k(const float* __restrict__ bih, const float* __restrict__ bhh,
                        float* __restrict__ bc)
{
    int i = blockIdx.x * 256 + threadIdx.x;
    if (i < 4 * Hh) bc[i] = bih[i] + bhh[i];
}

// h0 fp32 -> xh hi/lo at col 768
__global__ void hconv_k(const float* __restrict__ h, ushort_t* __restrict__ xhi,
                        ushort_t* __restrict__ xlo)
{
    int i = blockIdx.x * 256 + threadIdx.x;
    if (i >= Bb * Hh) return;
    int b = i / Hh, j = i % Hh;
    float v = h[i];
    ushort_t hb = f2bf(v);
    xhi[b * 1280 + 768 + j] = hb;
    xlo[b * 1280 + 768 + j] = f2bf(v - bf2f(hb));
}

// ---------------------------------------------------------------------------
// Attention scores: e[b][l] = sum_k tanh(enc[b,l,k]+dec[b,k])*v_att[k]
// grid (B, 2): each block 98 rows, 4 waves.
// ---------------------------------------------------------------------------
__global__ __launch_bounds__(256)
void attn_score_k(const ushort_t* __restrict__ enc, const float* __restrict__ dgb,
                  const float* __restrict__ v_att, float* __restrict__ ebuf)
{
    int b = blockIdx.x, half = blockIdx.y;
    __shared__ float dp[Hh], va[Hh];
    for (int i = threadIdx.x; i < Hh; i += 256) {
        dp[i] = dgb[b * 1024 + i];
        va[i] = v_att[i];
    }
    __syncthreads();
    int wv = threadIdx.x >> 6, ln = threadIdx.x & 63;
    int lbase = half * 98;
    const ushort_t* ep = enc + (size_t)b * Ll * Hh;
    for (int l = lbase + wv; l < lbase + 98; l += 4) {
        const ushort_t* row = ep + (size_t)l * Hh;
        float s = 0.f;
        #pragma unroll
        for (int r = 0; r < 8; ++r) {
            int k = r * 64 + ln;
            s += tanh_f(bf2f(row[k]) + dp[k]) * va[k];
        }
        #pragma unroll
        for (int o = 32; o; o >>= 1) s += __shfl_xor(s, o);
        if (ln == 0) ebuf[b * Ll + l] = s;
    }
}

// ---------------------------------------------------------------------------
// Softmax (redundant per half) + alphas/emb (half 0) + ctx*gate -> x hi/lo.
// grid (B, 2), 256 threads. Each half covers 256 e-columns.
// ---------------------------------------------------------------------------
template<bool IMGBF>
__global__ __launch_bounds__(256)
void attn_softctx_k(const float* __restrict__ ebuf, const float* __restrict__ dgb,
                    const ushort_t* __restrict__ img_bf, const float* __restrict__ img_f,
                    const float* __restrict__ emb, const int* __restrict__ captions,
                    float* __restrict__ alphas, long long alpha_stride,
                    ushort_t* __restrict__ xhi, ushort_t* __restrict__ xlo, int t)
{
    int b = blockIdx.x, half = blockIdx.y, tid = threadIdx.x;
    int wv = tid >> 6, ln = tid & 63;
    __shared__ float es[Ll], red[4];

    float v = (tid < Ll) ? ebuf[b * Ll + tid] : -1e30f;
    float m = v;
    #pragma unroll
    for (int o = 32; o; o >>= 1) m = fmaxf(m, __shfl_xor(m, o));
    if (ln == 0) red[wv] = m;
    __syncthreads();
    m = fmaxf(fmaxf(red[0], red[1]), fmaxf(red[2], red[3]));
    __syncthreads();
    float p = (tid < Ll) ? __expf(v - m) : 0.f;
    float s = p;
    #pragma unroll
    for (int o = 32; o; o >>= 1) s += __shfl_xor(s, o);
    if (ln == 0) red[wv] = s;
    __syncthreads();
    s = red[0] + red[1] + red[2] + red[3];
    float inv = 1.f / s;
    if (tid < Ll) {
        float a = p * inv;
        es[tid] = a;
        if (half == 0) alphas[(size_t)b * alpha_stride + tid] = a;
    }
    if (half == 0) {
        // x[b][0:256] = emb[captions[b,t]]
        float xv = emb[(size_t)captions[b * Tt + t] * Ee + tid];
        ushort_t hb = f2bf(xv);
        xhi[b * 1280 + tid] = hb;
        xlo[b * 1280 + tid] = f2bf(xv - bf2f(hb));
    }
    __syncthreads();

    int e = half * 256 + tid;
    float acc = 0.f;
    if (IMGBF) {
        const ushort_t* ib = img_bf + (size_t)b * Ll * ENCe + e;
        #pragma unroll 4
        for (int l = 0; l < Ll; ++l) acc = fmaf(es[l], bf2f(ib[(size_t)l * ENCe]), acc);
    } else {
        const float* ib = img_f + (size_t)b * Ll * ENCe + e;
        #pragma unroll 4
        for (int l = 0; l < Ll; ++l) acc = fmaf(es[l], ib[(size_t)l * ENCe], acc);
    }
    float xv = acc * dgb[b * 1024 + 512 + e];
    ushort_t hb = f2bf(xv);
    int j = Ee + e;
    xhi[b * 1280 + j] = hb;
    xlo[b * 1280 + j] = f2bf(xv - bf2f(hb));
}

// LSTM elementwise; writes c, h->xh (hi/lo) and h->hseq[t] (hi/lo)
__global__ void lstm_k(const float* __restrict__ gates, float* __restrict__ c,
                       ushort_t* __restrict__ xhi, ushort_t* __restrict__ xlo,
                       ushort_t* __restrict__ hseqH, ushort_t* __restrict__ hseqL, int t)
{
    int i = blockIdx.x * 256 + threadIdx.x;
    if (i >= Bb * Hh) return;
    int b = i / Hh, j = i % Hh;
    const float* g = gates + (size_t)b * 4 * Hh;
    float ig = sigm_f(g[j]);
    float fg = sigm_f(g[Hh + j]);
    float gg = tanh_f(g[2 * Hh + j]);
    float og = sigm_f(g[3 * Hh + j]);
    float cn = fg * c[i] + ig * gg;
    c[i] = cn;
    float hv = og * tanh_f(cn);
    ushort_t hb = f2bf(hv);
    ushort_t lb = f2bf(hv - bf2f(hb));
    xhi[b * 1280 + 768 + j] = hb;
    xlo[b * 1280 + 768 + j] = lb;
    size_t o = ((size_t)t * Bb + b) * Hh + j;
    hseqH[o] = hb;
    hseqL[o] = lb;
}

// ---------------------------------------------------------------------------
extern "C" void kernel_launch(void* const* d_in, const int* in_sizes, int n_in,
                              void* d_out, int out_size, void* d_ws, size_t ws_size,
                              hipStream_t stream)
{
    const float* img    = (const float*)d_in[0];
    const float* W_h    = (const float*)d_in[1];
    const float* b_h    = (const float*)d_in[2];
    const float* W_c    = (const float*)d_in[3];
    const float* b_c    = (const float*)d_in[4];
    const float* W_gate = (const float*)d_in[5];
    const float* b_gate = (const float*)d_in[6];
    const float* emb    = (const float*)d_in[7];
    const float* W_ae   = (const float*)d_in[8];
    const float* b_ae   = (const float*)d_in[9];
    const float* W_ad   = (const float*)d_in[10];
    const float* b_ad   = (const float*)d_in[11];
    const float* v_att  = (const float*)d_in[12];
    const float* W_ih   = (const float*)d_in[14];
    const float* b_ih   = (const float*)d_in[15];
    const float* W_hh   = (const float*)d_in[16];
    const float* b_hh   = (const float*)d_in[17];
    const float* W_out  = (const float*)d_in[18];
    const float* b_out  = (const float*)d_in[19];
    const int* captions = (const int*)d_in[20];

    float* out    = (float*)d_out;                       // [B,T,V]
    float* alphas = out + (size_t)Bb * Tt * Vv;          // [B,T,L]

    // ---- workspace allocator (256B aligned) ----
    char* p = (char*)d_ws;
    auto alloc = [&](size_t bytes) -> char* {
        char* r = p; p += (bytes + 255) & ~(size_t)255; return r;
    };
    const size_t szEnc   = (size_t)Bb * Ll * Hh * 2;      // 25.7 MB
    const size_t szWout  = (size_t)Vv * Hh * 2;           // 10.24 MB
    const size_t szWg    = (size_t)(4 * Hh) * 1280 * 2;   // 5.24 MB
    const size_t szWdg   = (size_t)1024 * Hh * 2;         // 1.05 MB
    const size_t szWae   = (size_t)Hh * Hh * 2;           // 0.52 MB
    const size_t szXh    = (size_t)Bb * 1280 * 2;         // 0.33 MB
    const size_t szHseq  = (size_t)Tt * Bb * Hh * 2;      // 2.62 MB
    const size_t szImg   = (size_t)Bb * Ll * ENCe * 2;    // 25.7 MB

    ushort_t* enc_hi = (ushort_t*)alloc(szEnc);
    ushort_t* WoutH  = (ushort_t*)alloc(szWout);
    ushort_t* WgH    = (ushort_t*)alloc(szWg);
    ushort_t* WdgH   = (ushort_t*)alloc(szWdg);
    ushort_t* WaeTH  = (ushort_t*)alloc(szWae);
    ushort_t* WaeTL  = (ushort_t*)alloc(szWae);
    ushort_t* xhH    = (ushort_t*)alloc(szXh);
    ushort_t* xhL    = (ushort_t*)alloc(szXh);
    ushort_t* hseqH  = (ushort_t*)alloc(szHseq);
    ushort_t* hseqL  = (ushort_t*)alloc(szHseq);
    float*    cbuf   = (float*)alloc((size_t)Bb * Hh * 4);
    float*    dgb    = (float*)alloc((size_t)Bb * 1024 * 4);
    float*    ebuf   = (float*)alloc((size_t)Bb * Ll * 4);
    float*    S      = (float*)alloc((size_t)Bb * 2048 * 4); // gates / fm+h0 union
    float*    bcomb  = (float*)alloc(4 * Hh * 4);

    auto tryAlloc = [&](size_t bytes) -> char* {
        size_t used = (size_t)(p - (char*)d_ws);
        size_t rounded = (bytes + 255) & ~(size_t)255;
        if (used + rounded > ws_size) return nullptr;
        return alloc(bytes);
    };
    ushort_t* WoutL = (ushort_t*)tryAlloc(szWout);
    ushort_t* WgL   = (ushort_t*)tryAlloc(szWg);
    ushort_t* WdgL  = (ushort_t*)tryAlloc(szWdg);
    ushort_t* imgH  = (ushort_t*)tryAlloc(szImg);
    ushort_t* imgL  = (ushort_t*)tryAlloc(szImg);

    float* fm  = S;                      // [B][512]
    float* h0b = S + Bb * ENCe;          // [B][512]
    float* gates = S;                    // [B][2048] (after h0 consumed)

    dim3 blk(256);
    const int NOSPLIT = 0x40000000;

    // ---- one-time weight conversion (transposed bf16 hi/lo) ----
    if (WoutL) convT_k<true ><<<dim3(157, 8), blk, 0, stream>>>(W_out, Hh, Vv, WoutH, WoutL, Hh, 0);
    else       convT_k<false><<<dim3(157, 8), blk, 0, stream>>>(W_out, Hh, Vv, WoutH, nullptr, Hh, 0);
    if (WgL) {
        convT_k<true ><<<dim3(32, 12), blk, 0, stream>>>(W_ih, 768, 2048, WgH, WgL, 1280, 0);
        convT_k<true ><<<dim3(32, 8),  blk, 0, stream>>>(W_hh, Hh,  2048, WgH, WgL, 1280, 768);
    } else {
        convT_k<false><<<dim3(32, 12), blk, 0, stream>>>(W_ih, 768, 2048, WgH, nullptr, 1280, 0);
        convT_k<false><<<dim3(32, 8),  blk, 0, stream>>>(W_hh, Hh,  2048, WgH, nullptr, 1280, 768);
    }
    if (WdgL) {
        convT_k<true ><<<dim3(8, 8), blk, 0, stream>>>(W_ad,   Hh, Hh, WdgH, WdgL, Hh, 0);
        convT_k<true ><<<dim3(8, 8), blk, 0, stream>>>(W_gate, Hh, ENCe, WdgH + (size_t)512 * Hh,
                                                       WdgL + (size_t)512 * Hh, Hh, 0);
    } else {
        convT_k<false><<<dim3(8, 8), blk, 0, stream>>>(W_ad,   Hh, Hh, WdgH, nullptr, Hh, 0);
        convT_k<false><<<dim3(8, 8), blk, 0, stream>>>(W_gate, Hh, ENCe, WdgH + (size_t)512 * Hh,
                                                       nullptr, Hh, 0);
    }

    bcomb_k<<<(4 * Hh + 255) / 256, blk, 0, stream>>>(b_ih, b_hh, bcomb);
    featmean_k<<<Bb, blk, 0, stream>>>(img, fm);

    // h0 = tanh(fm @ W_h + b_h) ; c0 = tanh(fm @ W_c + b_c)
    gemm_k<32, 2, 4, 1, 0><<<dim3(Hh / 32, Bb / 64), blk, 0, stream>>>(
        fm, ENCe, W_h, Hh, b_h, h0b, Hh, Bb, Hh, ENCe);
    gemm_k<32, 2, 4, 1, 0><<<dim3(Hh / 32, Bb / 64), blk, 0, stream>>>(
        fm, ENCe, W_c, Hh, b_c, cbuf, Hh, Bb, Hh, ENCe);
    hconv_k<<<(Bb * Hh + 255) / 256, blk, 0, stream>>>(h0b, xhH, xhL);

    // enc_proj = img @ W_ae + b_ae -> bf16
    if (imgL) {
        convbf2_k<<<2048, blk, 0, stream>>>(img, imgH, imgL, (long long)Bb * Ll * ENCe);
        convT_k<true><<<dim3(8, 8), blk, 0, stream>>>(W_ae, Hh, Hh, WaeTH, WaeTL, Hh, 0);
        mgemm_k<8, 2, 0, 0, true, true, false, false><<<dim3(4, 196), blk, 0, stream>>>(
            imgH, imgL, ENCe, WaeTH, WaeTL, Hh, b_ae, nullptr, NOSPLIT,
            enc_hi, Hh, 0, Hh, ENCe, 0);
    } else {
        if (imgH) convbf_k<<<2048, blk, 0, stream>>>(img, imgH, (long long)Bb * Ll * ENCe);
        gemm_k<64, 4, 4, 0, 1><<<dim3(Hh / 64, (Bb * Ll) / 64), blk, 0, stream>>>(
            img, ENCe, W_ae, Hh, b_ae, enc_hi, Hh, Bb * Ll, Hh, ENCe);
    }

    const ushort_t* hH = xhH + 768;  // h rows inside xh, lda=1280
    const ushort_t* hL = xhL + 768;

    for (int t = 0; t < Tt; ++t) {
        // dg = [h@W_ad + b_ad | sigmoid(h@W_gate + b_gate)]
        if (WdgL)
            mgemm_k<1, 1, 0, 2, true , false, false, false><<<dim3(16, 8), blk, 0, stream>>>(
                hH, hL, 1280, WdgH, WdgL, Hh, b_ad, b_gate, 512, dgb, 1024, 0, 1024, Hh, 0);
        else
            mgemm_k<1, 1, 0, 2, false, false, false, false><<<dim3(16, 8), blk, 0, stream>>>(
                hH, hL, 1280, WdgH, nullptr, Hh, b_ad, b_gate, 512, dgb, 1024, 0, 1024, Hh, 0);

        attn_score_k<<<dim3(Bb, 2), blk, 0, stream>>>(enc_hi, dgb, v_att, ebuf);
        if (imgH)
            attn_softctx_k<true ><<<dim3(Bb, 2), blk, 0, stream>>>(
                ebuf, dgb, imgH, nullptr, emb, captions,
                alphas + (size_t)t * Ll, (long long)Tt * Ll, xhH, xhL, t);
        else
            attn_softctx_k<false><<<dim3(Bb, 2), blk, 0, stream>>>(
                ebuf, dgb, nullptr, img, emb, captions,
                alphas + (size_t)t * Ll, (long long)Tt * Ll, xhH, xhL, t);

        // gates = [x|h] @ [W_ih;W_hh]^T + bcomb
        if (WgL)
            mgemm_k<1, 1, 0, 0, true , false, false, false><<<dim3(32, 8), blk, 0, stream>>>(
                xhH, xhL, 1280, WgH, WgL, 1280, bcomb, nullptr, NOSPLIT,
                gates, 2048, 0, 2048, 1280, 0);
        else
            mgemm_k<1, 1, 0, 0, false, false, false, false><<<dim3(32, 8), blk, 0, stream>>>(
                xhH, xhL, 1280, WgH, nullptr, 1280, bcomb, nullptr, NOSPLIT,
                gates, 2048, 0, 2048, 1280, 0);

        lstm_k<<<(Bb * Hh + 255) / 256, blk, 0, stream>>>(gates, cbuf, xhH, xhL,
                                                          hseqH, hseqL, t);
    }

    // Batched logits: [T*B, V] = hseq @ Wout^T + b_out, permuted into out[b][t][v]
    // 1D grid 79 n-strips x 20 m-blocks, XCD-swizzled for W_out L2 reuse.
    if (WoutL)
        mgemm_k<8, 2, 0, 0, true , false, true, true><<<dim3(79 * 20), blk, 0, stream>>>(
            hseqH, hseqL, Hh, WoutH, WoutL, Hh, b_out, nullptr, NOSPLIT,
            out, (long long)Tt * Vv, (long long)Vv, Vv, Hh, 20);
    else
        mgemm_k<8, 2, 0, 0, false, false, true, true><<<dim3(79 * 20), blk, 0, stream>>>(
            hseqH, hseqL, Hh, WoutH, nullptr, Hh, b_out, nullptr, NOSPLIT,
            out, (long long)Tt * Vv, (long long)Vv, Vv, Hh, 20);
}

// Round 5
// 1536.194 us; speedup vs baseline: 3.2179x; 1.3003x over previous
//
#include <hip/hip_runtime.h>
#include <math.h>

typedef unsigned short ushort_t;
typedef __attribute__((ext_vector_type(8))) short bf16x8;
typedef __attribute__((ext_vector_type(4))) float f32x4;

constexpr int Bb  = 128;
constexpr int Ll  = 196;
constexpr int ENCe= 512;
constexpr int Hh  = 512;
constexpr int Ee  = 256;
constexpr int Vv  = 10000;
constexpr int Tt  = 20;

#define DEV __device__ __forceinline__

DEV float sigm_f(float x) { return 1.f / (1.f + __expf(-x)); }
DEV float tanh_f(float x) {
    x = fminf(fmaxf(x, -15.f), 15.f);
    float e = __expf(2.f * x);
    return (e - 1.f) / (e + 1.f);
}
DEV ushort_t f2bf(float v) {
    unsigned u = __float_as_uint(v);
    return (ushort_t)((u + 0x7FFFu + ((u >> 16) & 1u)) >> 16);
}
DEV float bf2f(ushort_t h) { return __uint_as_float(((unsigned)h) << 16); }

// Packed-fragment layout for a logical [R][K] bf16 matrix (R rows, K cols):
//   element (r, k) lives at ((r>>4)*KS + (k>>5))*512 + (((k>>3)&3)*16 + (r&15))*8 + (k&7)
// where KS = K/32. A wave's MFMA fragment (rfrag, kstep) is then the 1 KB
// contiguous block at ((rfrag*KS + kstep)*64 + lane)*8 — lane l's 16 B chunk
// is exactly its mfma_f32_16x16x32_bf16 A/B operand.
DEV void store_xh(ushort_t* __restrict__ H, ushort_t* __restrict__ L,
                  int b, int k, float v)
{
    size_t idx = (((size_t)(b >> 4) * 40 + (k >> 5)) * 64
                  + ((k >> 3) & 3) * 16 + (b & 15)) * 8 + (k & 7);
    ushort_t hb = f2bf(v);
    H[idx] = hb;
    L[idx] = f2bf(v - bf2f(hb));
}

// ---------------------------------------------------------------------------
// fp32 tiled GEMM (h0/c0 + enc_proj fallback). OUTBF emits bf16.
// ---------------------------------------------------------------------------
template<int BN, int TM, int TN, int ACT1, int OUTBF>
__global__ __launch_bounds__(256)
void gemm_k(const float* __restrict__ A, int lda,
            const float* __restrict__ Wk, int ldw,
            const float* __restrict__ bias,
            void* __restrict__ Cv, long long ldc,
            int M, int N, int K)
{
    constexpr int BM = 64, BK = 16;
    constexpr int TX = BN / TN, TY = BM / TM;
    static_assert(TX * TY == 256, "bad tile config");
    __shared__ float As[BK][BM];
    __shared__ float Ws[BK][BN];

    const int tid = threadIdx.x;
    const int tx = tid % TX, ty = tid / TX;
    const int nb = blockIdx.x * BN, mb = blockIdx.y * BM;

    float acc[TM][TN] = {};
    const int am = tid >> 2;
    const int ak = (tid & 3) * 4;
    const int wn = tid % BN;
    const int wk0 = tid / BN;
    constexpr int WKSTEP = 256 / BN;

    for (int k0 = 0; k0 < K; k0 += BK) {
        float4 av = *(const float4*)&A[(size_t)(mb + am) * lda + k0 + ak];
        As[ak + 0][am] = av.x;
        As[ak + 1][am] = av.y;
        As[ak + 2][am] = av.z;
        As[ak + 3][am] = av.w;
        #pragma unroll
        for (int i = 0; i < BK / WKSTEP; ++i) {
            int kw = wk0 + i * WKSTEP;
            Ws[kw][wn] = (nb + wn < N) ? Wk[(size_t)(k0 + kw) * ldw + nb + wn] : 0.f;
        }
        __syncthreads();
        #pragma unroll
        for (int k = 0; k < BK; ++k) {
            float a[TM], w[TN];
            #pragma unroll
            for (int i = 0; i < TM; ++i) a[i] = As[k][ty * TM + i];
            #pragma unroll
            for (int j = 0; j < TN; ++j) w[j] = Ws[k][tx * TN + j];
            #pragma unroll
            for (int i = 0; i < TM; ++i)
                #pragma unroll
                for (int j = 0; j < TN; ++j)
                    acc[i][j] = fmaf(a[i], w[j], acc[i][j]);
        }
        __syncthreads();
    }

    #pragma unroll
    for (int i = 0; i < TM; ++i) {
        int m = mb + ty * TM + i;
        #pragma unroll
        for (int j = 0; j < TN; ++j) {
            int n = nb + tx * TN + j;
            if (n < N) {
                float v = acc[i][j];
                if (bias) v += bias[n];
                if (ACT1 == 1) v = tanh_f(v);
                if (OUTBF) ((ushort_t*)Cv)[(size_t)m * ldc + n] = f2bf(v);
                else       ((float*)Cv)[(size_t)m * ldc + n] = v;
            }
        }
    }
}

// ---------------------------------------------------------------------------
// Old strided MFMA GEMM (enc_proj only). A rows [M][lda], B [N][ldb].
// ---------------------------------------------------------------------------
template<int MT, int NT, bool BLO>
__global__ __launch_bounds__(256)
void mgemm_k(const ushort_t* __restrict__ Ahi, const ushort_t* __restrict__ Alo, int lda,
             const ushort_t* __restrict__ Bhi, const ushort_t* __restrict__ Blo, int ldb,
             const float* __restrict__ bias,
             ushort_t* __restrict__ C, long long ldc, int N, int K)
{
    const int wv = threadIdx.x >> 6, lane = threadIdx.x & 63;
    const int n0 = (blockIdx.x * 4 + wv) * (16 * NT);
    if (n0 >= N) return;
    const int m0 = blockIdx.y * (MT * 16);
    const int col = lane & 15, kq = (lane >> 4) * 8;

    const ushort_t* bh[NT];
    const ushort_t* bl[NT];
    #pragma unroll
    for (int ct = 0; ct < NT; ++ct) {
        bh[ct] = Bhi + (size_t)(n0 + ct * 16 + col) * ldb + kq;
        bl[ct] = BLO ? (Blo + (size_t)(n0 + ct * 16 + col) * ldb + kq) : nullptr;
    }
    const ushort_t* ah[MT];
    const ushort_t* al[MT];
    #pragma unroll
    for (int mt = 0; mt < MT; ++mt) {
        size_t off = (size_t)(m0 + mt * 16 + col) * lda + kq;
        ah[mt] = Ahi + off;
        al[mt] = Alo + off;
    }

    f32x4 acc[NT][MT];
    #pragma unroll
    for (int ct = 0; ct < NT; ++ct)
        #pragma unroll
        for (int mt = 0; mt < MT; ++mt) acc[ct][mt] = (f32x4){0.f, 0.f, 0.f, 0.f};

    for (int k0 = 0; k0 < K; k0 += 32) {
        bf16x8 Bh[NT], Bl[NT];
        #pragma unroll
        for (int ct = 0; ct < NT; ++ct) {
            Bh[ct] = *(const bf16x8*)bh[ct]; bh[ct] += 32;
            if (BLO) { Bl[ct] = *(const bf16x8*)bl[ct]; bl[ct] += 32; }
        }
        #pragma unroll
        for (int mt = 0; mt < MT; ++mt) {
            bf16x8 afh = *(const bf16x8*)ah[mt]; ah[mt] += 32;
            bf16x8 afl = *(const bf16x8*)al[mt]; al[mt] += 32;
            #pragma unroll
            for (int ct = 0; ct < NT; ++ct) {
                acc[ct][mt] = __builtin_amdgcn_mfma_f32_16x16x32_bf16(afh, Bh[ct], acc[ct][mt], 0, 0, 0);
                acc[ct][mt] = __builtin_amdgcn_mfma_f32_16x16x32_bf16(afl, Bh[ct], acc[ct][mt], 0, 0, 0);
                if (BLO)
                    acc[ct][mt] = __builtin_amdgcn_mfma_f32_16x16x32_bf16(afh, Bl[ct], acc[ct][mt], 0, 0, 0);
            }
        }
    }

    #pragma unroll
    for (int ct = 0; ct < NT; ++ct) {
        const int nc = n0 + ct * 16 + col;
        if (nc >= N) continue;
        float bv = bias ? bias[nc] : 0.f;
        #pragma unroll
        for (int mt = 0; mt < MT; ++mt)
            #pragma unroll
            for (int r = 0; r < 4; ++r) {
                int row = m0 + mt * 16 + (lane >> 4) * 4 + r;
                C[(size_t)row * ldc + nc] = f2bf(acc[ct][mt][r] + bv);
            }
    }
}

// ---------------------------------------------------------------------------
// Packed-fragment MFMA GEMM with register double-buffer prefetch.
// A packed hi/lo (frag stride aFS elems), B packed hi/lo (stride bFS).
// W2D: 2x2 wave grid (block tile 2MT x 2NT frags); else 4 waves along N.
// PERM: C row m = t*128+b -> out[b][t][:] (nontemporal).
// XSWZ: 1D grid nblk*mblks, bijective XCD swizzle, by = lin % mblks.
// ---------------------------------------------------------------------------
template<int MT, int NT, int ACT1, int ACT2, bool BLO, bool PERM, bool XSWZ, bool W2D>
__global__ __launch_bounds__(256)
void mgemm_pk(const ushort_t* __restrict__ AH, const ushort_t* __restrict__ AL, int aFS,
              const ushort_t* __restrict__ BH, const ushort_t* __restrict__ BL, int bFS,
              const float* __restrict__ bias, const float* __restrict__ bias2, int N1,
              float* __restrict__ C, long long ldc, long long ldc2,
              int Nfrags, int Ntot, int nsteps, int mblks)
{
    int bx, by;
    if (XSWZ) {
        int nwg = gridDim.x, orig = blockIdx.x;
        int xcd = orig & 7, idx = orig >> 3;
        int q = nwg >> 3, r = nwg & 7;
        int lin = (xcd < r ? xcd * (q + 1) : r * (q + 1) + (xcd - r) * q) + idx;
        bx = lin / mblks; by = lin - bx * mblks;
    } else { bx = blockIdx.x; by = blockIdx.y; }

    const int wv = threadIdx.x >> 6, lane = threadIdx.x & 63;
    int nf0, mf0;
    if (W2D) {
        nf0 = (bx * 2 + (wv & 1)) * NT;
        mf0 = by * (2 * MT) + (wv >> 1) * MT;
    } else {
        nf0 = (bx * 4 + wv) * NT;
        mf0 = by * MT;
    }
    if (nf0 >= Nfrags) return;
    const int col = lane & 15;
    const int lofs = lane * 8;

    const ushort_t *paH[MT], *paL[MT], *pbH[NT], *pbL[NT];
    #pragma unroll
    for (int mt = 0; mt < MT; ++mt) {
        paH[mt] = AH + (size_t)(mf0 + mt) * aFS + lofs;
        paL[mt] = AL + (size_t)(mf0 + mt) * aFS + lofs;
    }
    #pragma unroll
    for (int ct = 0; ct < NT; ++ct) {
        int nf = nf0 + ct; if (nf > Nfrags - 1) nf = Nfrags - 1;
        pbH[ct] = BH + (size_t)nf * bFS + lofs;
        pbL[ct] = BLO ? (BL + (size_t)nf * bFS + lofs) : pbH[ct];
    }

    f32x4 acc[MT][NT];
    #pragma unroll
    for (int mt = 0; mt < MT; ++mt)
        #pragma unroll
        for (int ct = 0; ct < NT; ++ct) acc[mt][ct] = (f32x4){0.f, 0.f, 0.f, 0.f};

    auto LOADF = [&](bf16x8 (&A0)[MT], bf16x8 (&A1)[MT],
                     bf16x8 (&B0)[NT], bf16x8 (&B1)[NT], int i) {
        size_t o = (size_t)i * 512;
        #pragma unroll
        for (int mt = 0; mt < MT; ++mt) {
            A0[mt] = *(const bf16x8*)(paH[mt] + o);
            A1[mt] = *(const bf16x8*)(paL[mt] + o);
        }
        #pragma unroll
        for (int ct = 0; ct < NT; ++ct) {
            B0[ct] = *(const bf16x8*)(pbH[ct] + o);
            if (BLO) B1[ct] = *(const bf16x8*)(pbL[ct] + o);
        }
    };
    auto COMPF = [&](bf16x8 (&A0)[MT], bf16x8 (&A1)[MT],
                     bf16x8 (&B0)[NT], bf16x8 (&B1)[NT]) {
        #pragma unroll
        for (int mt = 0; mt < MT; ++mt)
            #pragma unroll
            for (int ct = 0; ct < NT; ++ct) {
                acc[mt][ct] = __builtin_amdgcn_mfma_f32_16x16x32_bf16(A0[mt], B0[ct], acc[mt][ct], 0, 0, 0);
                acc[mt][ct] = __builtin_amdgcn_mfma_f32_16x16x32_bf16(A1[mt], B0[ct], acc[mt][ct], 0, 0, 0);
                if (BLO)
                    acc[mt][ct] = __builtin_amdgcn_mfma_f32_16x16x32_bf16(A0[mt], B1[ct], acc[mt][ct], 0, 0, 0);
            }
    };

    // 2-phase software pipeline (nsteps must be even; 16 and 40 both are)
    bf16x8 xa0[MT], xa1[MT], xb0[NT], xb1[NT];
    bf16x8 ya0[MT], ya1[MT], yb0[NT], yb1[NT];
    LOADF(xa0, xa1, xb0, xb1, 0);
    for (int i = 0; i < nsteps; i += 2) {
        LOADF(ya0, ya1, yb0, yb1, i + 1);
        COMPF(xa0, xa1, xb0, xb1);
        if (i + 2 < nsteps) LOADF(xa0, xa1, xb0, xb1, i + 2);
        COMPF(ya0, ya1, yb0, yb1);
    }

    #pragma unroll
    for (int ct = 0; ct < NT; ++ct) {
        const int nc = (nf0 + ct) * 16 + col;
        if (nc >= Ntot) continue;
        const bool ns = ((nf0 + ct) * 16 >= N1);
        float bv = ns ? (bias2 ? bias2[nc - N1] : 0.f) : (bias ? bias[nc] : 0.f);
        const int act = ns ? ACT2 : ACT1;
        #pragma unroll
        for (int mt = 0; mt < MT; ++mt)
            #pragma unroll
            for (int r = 0; r < 4; ++r) {
                int row = (mf0 + mt) * 16 + (lane >> 4) * 4 + r;
                float v = acc[mt][ct][r] + bv;
                if (act == 1)      v = tanh_f(v);
                else if (act == 2) v = sigm_f(v);
                size_t off = PERM ? ((size_t)(row & 127) * ldc + (size_t)(row >> 7) * ldc2 + nc)
                                  : ((size_t)row * ldc + nc);
                if (PERM) __builtin_nontemporal_store(v, &C[off]);
                else      C[off] = v;
            }
    }
}

// ---------------------------------------------------------------------------
// Weight transpose+convert into PACKED-FRAGMENT layout.
// W[K][N] fp32; dest frag (nf+nfOfs, ks+ksOfs) within a KSfull-deep matrix.
// One thread per (nf, ks, lane); grid.x = nfCnt*KSr*64/256 exactly.
// ---------------------------------------------------------------------------
template<bool LO>
__global__ __launch_bounds__(256)
void convT_pk(const float* __restrict__ W, int N, int KSr,
              ushort_t* __restrict__ PH, ushort_t* __restrict__ PL,
              int KSfull, int ksOfs, int nfOfs)
{
    int tid = blockIdx.x * 256 + threadIdx.x;
    int lane = tid & 63;
    int rest = tid >> 6;
    int ks = rest % KSr;
    int nf = rest / KSr;
    const float* src = W + (size_t)(ks * 32 + ((lane >> 4) & 3) * 8) * N
                         + nf * 16 + (lane & 15);
    size_t dbase = (((size_t)(nf + nfOfs) * KSfull + ks + ksOfs) * 64 + lane) * 8;
    #pragma unroll
    for (int jj = 0; jj < 8; ++jj) {
        float v = src[(size_t)jj * N];
        ushort_t h = f2bf(v);
        PH[dbase + jj] = h;
        if (LO) PL[dbase + jj] = f2bf(v - bf2f(h));
    }
}

// ---------------------------------------------------------------------------
// Transpose + convert (strided [N][ldt] layout) — for W_ae only.
// ---------------------------------------------------------------------------
template<bool LO>
__global__ __launch_bounds__(256)
void convT_k(const float* __restrict__ W, int K, int N,
             ushort_t* __restrict__ Thi, ushort_t* __restrict__ Tlo,
             int ldt, int kofs)
{
    __shared__ float tile[64][65];
    int n0 = blockIdx.x * 64, k0 = blockIdx.y * 64;
    int c = threadIdx.x & 63, r0 = threadIdx.x >> 6;
    #pragma unroll
    for (int i = 0; i < 16; ++i) {
        int r = r0 * 16 + i;
        tile[r][c] = (n0 + c < N) ? W[(size_t)(k0 + r) * N + n0 + c] : 0.f;
    }
    __syncthreads();
    int nr = threadIdx.x >> 2, kc = (threadIdx.x & 3) * 16;
    if (n0 + nr < N) {
        ushort_t* ph = Thi + (size_t)(n0 + nr) * ldt + kofs + k0 + kc;
        ushort_t* pl = LO ? (Tlo + (size_t)(n0 + nr) * ldt + kofs + k0 + kc) : nullptr;
        #pragma unroll
        for (int j = 0; j < 16; ++j) {
            float v = tile[kc + j][nr];
            ushort_t h = f2bf(v);
            ph[j] = h;
            if (LO) pl[j] = f2bf(v - bf2f(h));
        }
    }
}

// elementwise fp32 -> bf16 (hi only)
__global__ void convbf_k(const float* __restrict__ src, ushort_t* __restrict__ dst,
                         long long n)
{
    long long i = (long long)(blockIdx.x * 256 + threadIdx.x) * 4;
    long long stride = (long long)gridDim.x * 1024;
    for (; i + 3 < n; i += stride) {
        float4 v = *(const float4*)&src[i];
        dst[i + 0] = f2bf(v.x); dst[i + 1] = f2bf(v.y);
        dst[i + 2] = f2bf(v.z); dst[i + 3] = f2bf(v.w);
    }
}

// elementwise fp32 -> bf16 hi + lo
__global__ void convbf2_k(const float* __restrict__ src, ushort_t* __restrict__ hi,
                          ushort_t* __restrict__ lo, long long n)
{
    long long i = (long long)(blockIdx.x * 256 + threadIdx.x) * 4;
    long long stride = (long long)gridDim.x * 1024;
    for (; i + 3 < n; i += stride) {
        float4 v = *(const float4*)&src[i];
        float vs[4] = {v.x, v.y, v.z, v.w};
        #pragma unroll
        for (int j = 0; j < 4; ++j) {
            ushort_t h = f2bf(vs[j]);
            hi[i + j] = h;
            lo[i + j] = f2bf(vs[j] - bf2f(h));
        }
    }
}

// feat_mean
__global__ __launch_bounds__(256)
void featmean_k(const float* __restrict__ img, float* __restrict__ fm)
{
    int b = blockIdx.x, tid = threadIdx.x;
    const float* base = img + (size_t)b * Ll * ENCe;
    for (int e = tid; e < ENCe; e += 256) {
        float s = 0.f;
        for (int l = 0; l < Ll; ++l) s += base[l * ENCe + e];
        fm[b * ENCe + e] = s * (1.f / (float)Ll);
    }
}

__global__ void bcomb_k(const float* __restrict__ bih, const float* __restrict__ bhh,
                        float* __restrict__ bc)
{
    int i = blockIdx.x * 256 + threadIdx.x;
    if (i < 4 * Hh) bc[i] = bih[i] + bhh[i];
}

// h0 fp32 -> xh packed at col 768+j
__global__ void hconv_k(const float* __restrict__ h, ushort_t* __restrict__ xhi,
                        ushort_t* __restrict__ xlo)
{
    int i = blockIdx.x * 256 + threadIdx.x;
    if (i >= Bb * Hh) return;
    int b = i / Hh, j = i % Hh;
    store_xh(xhi, xlo, b, 768 + j, h[i]);
}

// ---------------------------------------------------------------------------
// Attention scores: e[b][l] = sum_k tanh(enc[b,l,k]+dec[b,k])*v_att[k]
// grid (B, 2): each block 98 rows, 4 waves.
// ---------------------------------------------------------------------------
__global__ __launch_bounds__(256)
void attn_score_k(const ushort_t* __restrict__ enc, const float* __restrict__ dgb,
                  const float* __restrict__ v_att, float* __restrict__ ebuf)
{
    int b = blockIdx.x, half = blockIdx.y;
    __shared__ float dp[Hh], va[Hh];
    for (int i = threadIdx.x; i < Hh; i += 256) {
        dp[i] = dgb[b * 1024 + i];
        va[i] = v_att[i];
    }
    __syncthreads();
    int wv = threadIdx.x >> 6, ln = threadIdx.x & 63;
    int lbase = half * 98;
    const ushort_t* ep = enc + (size_t)b * Ll * Hh;
    for (int l = lbase + wv; l < lbase + 98; l += 4) {
        const ushort_t* row = ep + (size_t)l * Hh;
        float s = 0.f;
        #pragma unroll
        for (int r = 0; r < 8; ++r) {
            int k = r * 64 + ln;
            s += tanh_f(bf2f(row[k]) + dp[k]) * va[k];
        }
        #pragma unroll
        for (int o = 32; o; o >>= 1) s += __shfl_xor(s, o);
        if (ln == 0) ebuf[b * Ll + l] = s;
    }
}

// ---------------------------------------------------------------------------
// Softmax (redundant per half) + alphas/emb (half 0) + ctx*gate -> packed x.
// grid (B, 2), 256 threads. Each half covers 256 e-columns.
// ---------------------------------------------------------------------------
template<bool IMGBF>
__global__ __launch_bounds__(256)
void attn_softctx_k(const float* __restrict__ ebuf, const float* __restrict__ dgb,
                    const ushort_t* __restrict__ img_bf, const float* __restrict__ img_f,
                    const float* __restrict__ emb, const int* __restrict__ captions,
                    float* __restrict__ alphas, long long alpha_stride,
                    ushort_t* __restrict__ xhi, ushort_t* __restrict__ xlo, int t)
{
    int b = blockIdx.x, half = blockIdx.y, tid = threadIdx.x;
    int wv = tid >> 6, ln = tid & 63;
    __shared__ float es[Ll], red[4];

    float v = (tid < Ll) ? ebuf[b * Ll + tid] : -1e30f;
    float m = v;
    #pragma unroll
    for (int o = 32; o; o >>= 1) m = fmaxf(m, __shfl_xor(m, o));
    if (ln == 0) red[wv] = m;
    __syncthreads();
    m = fmaxf(fmaxf(red[0], red[1]), fmaxf(red[2], red[3]));
    __syncthreads();
    float p = (tid < Ll) ? __expf(v - m) : 0.f;
    float s = p;
    #pragma unroll
    for (int o = 32; o; o >>= 1) s += __shfl_xor(s, o);
    if (ln == 0) red[wv] = s;
    __syncthreads();
    s = red[0] + red[1] + red[2] + red[3];
    float inv = 1.f / s;
    if (tid < Ll) {
        float a = p * inv;
        es[tid] = a;
        if (half == 0) alphas[(size_t)b * alpha_stride + tid] = a;
    }
    if (half == 0) {
        float xv = emb[(size_t)captions[b * Tt + t] * Ee + tid];
        store_xh(xhi, xlo, b, tid, xv);
    }
    __syncthreads();

    int e = half * 256 + tid;
    float acc = 0.f;
    if (IMGBF) {
        const ushort_t* ib = img_bf + (size_t)b * Ll * ENCe + e;
        #pragma unroll 4
        for (int l = 0; l < Ll; ++l) acc = fmaf(es[l], bf2f(ib[(size_t)l * ENCe]), acc);
    } else {
        const float* ib = img_f + (size_t)b * Ll * ENCe + e;
        #pragma unroll 4
        for (int l = 0; l < Ll; ++l) acc = fmaf(es[l], ib[(size_t)l * ENCe], acc);
    }
    float xv = acc * dgb[b * 1024 + 512 + e];
    store_xh(xhi, xlo, b, 256 + e, xv);
}

// LSTM elementwise; writes c, h -> packed xh[768+j] and packed hseq row t*128+b
__global__ void lstm_k(const float* __restrict__ gates, float* __restrict__ c,
                       ushort_t* __restrict__ xhi, ushort_t* __restrict__ xlo,
                       ushort_t* __restrict__ hseqH, ushort_t* __restrict__ hseqL, int t)
{
    int i = blockIdx.x * 256 + threadIdx.x;
    if (i >= Bb * Hh) return;
    int b = i / Hh, j = i % Hh;
    const float* g = gates + (size_t)b * 4 * Hh;
    float ig = sigm_f(g[j]);
    float fg = sigm_f(g[Hh + j]);
    float gg = tanh_f(g[2 * Hh + j]);
    float og = sigm_f(g[3 * Hh + j]);
    float cn = fg * c[i] + ig * gg;
    c[i] = cn;
    float hv = og * tanh_f(cn);
    store_xh(xhi, xlo, b, 768 + j, hv);
    ushort_t hb = f2bf(hv);
    size_t hidx = (((size_t)(t * 8 + (b >> 4)) * 16 + (j >> 5)) * 64
                   + ((j >> 3) & 3) * 16 + (b & 15)) * 8 + (j & 7);
    hseqH[hidx] = hb;
    hseqL[hidx] = f2bf(hv - bf2f(hb));
}

// ---------------------------------------------------------------------------
extern "C" void kernel_launch(void* const* d_in, const int* in_sizes, int n_in,
                              void* d_out, int out_size, void* d_ws, size_t ws_size,
                              hipStream_t stream)
{
    const float* img    = (const float*)d_in[0];
    const float* W_h    = (const float*)d_in[1];
    const float* b_h    = (const float*)d_in[2];
    const float* W_c    = (const float*)d_in[3];
    const float* b_c    = (const float*)d_in[4];
    const float* W_gate = (const float*)d_in[5];
    const float* b_gate = (const float*)d_in[6];
    const float* emb    = (const float*)d_in[7];
    const float* W_ae   = (const float*)d_in[8];
    const float* b_ae   = (const float*)d_in[9];
    const float* W_ad   = (const float*)d_in[10];
    const float* b_ad   = (const float*)d_in[11];
    const float* v_att  = (const float*)d_in[12];
    const float* W_ih   = (const float*)d_in[14];
    const float* b_ih   = (const float*)d_in[15];
    const float* W_hh   = (const float*)d_in[16];
    const float* b_hh   = (const float*)d_in[17];
    const float* W_out  = (const float*)d_in[18];
    const float* b_out  = (const float*)d_in[19];
    const int* captions = (const int*)d_in[20];

    float* out    = (float*)d_out;                       // [B,T,V]
    float* alphas = out + (size_t)Bb * Tt * Vv;          // [B,T,L]

    // ---- workspace allocator (256B aligned) ----
    char* p = (char*)d_ws;
    auto alloc = [&](size_t bytes) -> char* {
        char* r = p; p += (bytes + 255) & ~(size_t)255; return r;
    };
    const size_t szEnc   = (size_t)Bb * Ll * Hh * 2;      // 25.7 MB
    const size_t szWout  = (size_t)625 * 16 * 512 * 2;    // 10.24 MB (packed)
    const size_t szWg    = (size_t)128 * 40 * 512 * 2;    // 5.24 MB (packed)
    const size_t szWdg   = (size_t)64 * 16 * 512 * 2;     // 1.05 MB (packed)
    const size_t szWae   = (size_t)Hh * Hh * 2;           // 0.52 MB
    const size_t szXh    = (size_t)8 * 40 * 512 * 2;      // 0.33 MB (packed)
    const size_t szHseq  = (size_t)160 * 16 * 512 * 2;    // 2.62 MB (packed)
    const size_t szImg   = (size_t)Bb * Ll * ENCe * 2;    // 25.7 MB

    ushort_t* enc_hi  = (ushort_t*)alloc(szEnc);
    ushort_t* WoutPkH = (ushort_t*)alloc(szWout);
    ushort_t* WgPkH   = (ushort_t*)alloc(szWg);
    ushort_t* WdgPkH  = (ushort_t*)alloc(szWdg);
    ushort_t* WaeTH   = (ushort_t*)alloc(szWae);
    ushort_t* WaeTL   = (ushort_t*)alloc(szWae);
    ushort_t* xhPkH   = (ushort_t*)alloc(szXh);
    ushort_t* xhPkL   = (ushort_t*)alloc(szXh);
    ushort_t* hseqPkH = (ushort_t*)alloc(szHseq);
    ushort_t* hseqPkL = (ushort_t*)alloc(szHseq);
    float*    cbuf    = (float*)alloc((size_t)Bb * Hh * 4);
    float*    dgb     = (float*)alloc((size_t)Bb * 1024 * 4);
    float*    ebuf    = (float*)alloc((size_t)Bb * Ll * 4);
    float*    S       = (float*)alloc((size_t)Bb * 2048 * 4); // gates / fm+h0 union
    float*    bcomb   = (float*)alloc(4 * Hh * 4);

    auto tryAlloc = [&](size_t bytes) -> char* {
        size_t used = (size_t)(p - (char*)d_ws);
        size_t rounded = (bytes + 255) & ~(size_t)255;
        if (used + rounded > ws_size) return nullptr;
        return alloc(bytes);
    };
    ushort_t* WoutPkL = (ushort_t*)tryAlloc(szWout);
    ushort_t* WgPkL   = (ushort_t*)tryAlloc(szWg);
    ushort_t* WdgPkL  = (ushort_t*)tryAlloc(szWdg);
    ushort_t* imgH    = (ushort_t*)tryAlloc(szImg);
    ushort_t* imgL    = (ushort_t*)tryAlloc(szImg);

    float* fm  = S;                      // [B][512]
    float* h0b = S + Bb * ENCe;          // [B][512]
    float* gates = S;                    // [B][2048] (after h0 consumed)

    dim3 blk(256);
    const int NOSPLIT = 0x40000000;
    const int aFSxh   = 40 * 512;   // xh packed frag stride (K=1280)
    const int aFSh    = 16 * 512;   // hseq packed frag stride (K=512)

    // ---- one-time weight conversion into packed-fragment bf16 hi/lo ----
    if (WoutPkL) convT_pk<true ><<<2500, blk, 0, stream>>>(W_out, Vv, 16, WoutPkH, WoutPkL, 16, 0, 0);
    else         convT_pk<false><<<2500, blk, 0, stream>>>(W_out, Vv, 16, WoutPkH, nullptr, 16, 0, 0);
    if (WgPkL) {
        convT_pk<true ><<<768, blk, 0, stream>>>(W_ih, 2048, 24, WgPkH, WgPkL, 40, 0, 0);
        convT_pk<true ><<<512, blk, 0, stream>>>(W_hh, 2048, 16, WgPkH, WgPkL, 40, 24, 0);
    } else {
        convT_pk<false><<<768, blk, 0, stream>>>(W_ih, 2048, 24, WgPkH, nullptr, 40, 0, 0);
        convT_pk<false><<<512, blk, 0, stream>>>(W_hh, 2048, 16, WgPkH, nullptr, 40, 24, 0);
    }
    if (WdgPkL) {
        convT_pk<true ><<<128, blk, 0, stream>>>(W_ad,   Hh, 16, WdgPkH, WdgPkL, 16, 0, 0);
        convT_pk<true ><<<128, blk, 0, stream>>>(W_gate, Hh, 16, WdgPkH, WdgPkL, 16, 0, 32);
    } else {
        convT_pk<false><<<128, blk, 0, stream>>>(W_ad,   Hh, 16, WdgPkH, nullptr, 16, 0, 0);
        convT_pk<false><<<128, blk, 0, stream>>>(W_gate, Hh, 16, WdgPkH, nullptr, 16, 0, 32);
    }

    bcomb_k<<<(4 * Hh + 255) / 256, blk, 0, stream>>>(b_ih, b_hh, bcomb);
    featmean_k<<<Bb, blk, 0, stream>>>(img, fm);

    // h0 = tanh(fm @ W_h + b_h) ; c0 = tanh(fm @ W_c + b_c)
    gemm_k<32, 2, 4, 1, 0><<<dim3(Hh / 32, Bb / 64), blk, 0, stream>>>(
        fm, ENCe, W_h, Hh, b_h, h0b, Hh, Bb, Hh, ENCe);
    gemm_k<32, 2, 4, 1, 0><<<dim3(Hh / 32, Bb / 64), blk, 0, stream>>>(
        fm, ENCe, W_c, Hh, b_c, cbuf, Hh, Bb, Hh, ENCe);
    hconv_k<<<(Bb * Hh + 255) / 256, blk, 0, stream>>>(h0b, xhPkH, xhPkL);

    // enc_proj = img @ W_ae + b_ae -> bf16 (strided-layout MFMA path)
    if (imgL) {
        convbf2_k<<<2048, blk, 0, stream>>>(img, imgH, imgL, (long long)Bb * Ll * ENCe);
        convT_k<true><<<dim3(8, 8), blk, 0, stream>>>(W_ae, Hh, Hh, WaeTH, WaeTL, Hh, 0);
        mgemm_k<8, 2, true><<<dim3(4, 196), blk, 0, stream>>>(
            imgH, imgL, ENCe, WaeTH, WaeTL, Hh, b_ae, enc_hi, Hh, Hh, ENCe);
    } else {
        if (imgH) convbf_k<<<2048, blk, 0, stream>>>(img, imgH, (long long)Bb * Ll * ENCe);
        gemm_k<64, 4, 4, 0, 1><<<dim3(Hh / 64, (Bb * Ll) / 64), blk, 0, stream>>>(
            img, ENCe, W_ae, Hh, b_ae, enc_hi, Hh, Bb * Ll, Hh, ENCe);
    }

    for (int t = 0; t < Tt; ++t) {
        // dg = [h@W_ad + b_ad | sigmoid(h@W_gate + b_gate)]
        // A = packed xh, ks range 24..39 (the h columns)
        if (WdgPkL)
            mgemm_pk<1, 1, 0, 2, true , false, false, false><<<dim3(16, 8), blk, 0, stream>>>(
                xhPkH + 24 * 512, xhPkL + 24 * 512, aFSxh, WdgPkH, WdgPkL, 16 * 512,
                b_ad, b_gate, 512, dgb, 1024, 0, 64, 1024, 16, 0);
        else
            mgemm_pk<1, 1, 0, 2, false, false, false, false><<<dim3(16, 8), blk, 0, stream>>>(
                xhPkH + 24 * 512, xhPkL + 24 * 512, aFSxh, WdgPkH, nullptr, 16 * 512,
                b_ad, b_gate, 512, dgb, 1024, 0, 64, 1024, 16, 0);

        attn_score_k<<<dim3(Bb, 2), blk, 0, stream>>>(enc_hi, dgb, v_att, ebuf);
        if (imgH)
            attn_softctx_k<true ><<<dim3(Bb, 2), blk, 0, stream>>>(
                ebuf, dgb, imgH, nullptr, emb, captions,
                alphas + (size_t)t * Ll, (long long)Tt * Ll, xhPkH, xhPkL, t);
        else
            attn_softctx_k<false><<<dim3(Bb, 2), blk, 0, stream>>>(
                ebuf, dgb, nullptr, img, emb, captions,
                alphas + (size_t)t * Ll, (long long)Tt * Ll, xhPkH, xhPkL, t);

        // gates = [x|h] @ [W_ih;W_hh]^T + bcomb   (K=1280, packed both sides)
        if (WgPkL)
            mgemm_pk<1, 1, 0, 0, true , false, false, false><<<dim3(32, 8), blk, 0, stream>>>(
                xhPkH, xhPkL, aFSxh, WgPkH, WgPkL, 40 * 512,
                bcomb, nullptr, NOSPLIT, gates, 2048, 0, 128, 2048, 40, 0);
        else
            mgemm_pk<1, 1, 0, 0, false, false, false, false><<<dim3(32, 8), blk, 0, stream>>>(
                xhPkH, xhPkL, aFSxh, WgPkH, nullptr, 40 * 512,
                bcomb, nullptr, NOSPLIT, gates, 2048, 0, 128, 2048, 40, 0);

        lstm_k<<<(Bb * Hh + 255) / 256, blk, 0, stream>>>(gates, cbuf, xhPkH, xhPkL,
                                                          hseqPkH, hseqPkL, t);
    }

    // Batched logits: [2560, 10000] = hseq @ Wout^T + b_out -> out[b][t][v]
    // 2x2 wave grid, block tile 128x128; grid 79 n-strips x 20 m-blocks,
    // XCD-swizzled (consecutive linear ids share one n-strip -> W_out L2 reuse)
    if (WoutPkL)
        mgemm_pk<4, 4, 0, 0, true , true, true, true><<<dim3(79 * 20), blk, 0, stream>>>(
            hseqPkH, hseqPkL, aFSh, WoutPkH, WoutPkL, aFSh,
            b_out, nullptr, NOSPLIT, out, (long long)Tt * Vv, (long long)Vv,
            625, Vv, 16, 20);
    else
        mgemm_pk<4, 4, 0, 0, false, true, true, true><<<dim3(79 * 20), blk, 0, stream>>>(
            hseqPkH, hseqPkL, aFSh, WoutPkH, nullptr, aFSh,
            b_out, nullptr, NOSPLIT, out, (long long)Tt * Vv, (long long)Vv,
            625, Vv, 16, 20);
}

// Round 6
// 1396.199 us; speedup vs baseline: 3.5406x; 1.1003x over previous
//
#include <hip/hip_runtime.h>
#include <math.h>

typedef unsigned short ushort_t;
typedef __attribute__((ext_vector_type(8))) short bf16x8;
typedef __attribute__((ext_vector_type(4))) float f32x4;

constexpr int Bb  = 128;
constexpr int Ll  = 196;
constexpr int ENCe= 512;
constexpr int Hh  = 512;
constexpr int Ee  = 256;
constexpr int Vv  = 10000;
constexpr int Tt  = 20;

#define DEV __device__ __forceinline__

DEV float sigm_f(float x) { return 1.f / (1.f + __expf(-x)); }
DEV float tanh_f(float x) {
    x = fminf(fmaxf(x, -15.f), 15.f);
    float e = __expf(2.f * x);
    return (e - 1.f) / (e + 1.f);
}
DEV ushort_t f2bf(float v) {
    unsigned u = __float_as_uint(v);
    return (ushort_t)((u + 0x7FFFu + ((u >> 16) & 1u)) >> 16);
}
DEV float bf2f(ushort_t h) { return __uint_as_float(((unsigned)h) << 16); }

// Packed-fragment layout for a logical [R][K] bf16 matrix:
//   (r,k) -> ((r>>4)*KS + (k>>5))*512 + (((k>>3)&3)*16 + (r&15))*8 + (k&7)
// A wave's MFMA fragment (rfrag, kstep) is the contiguous 1 KB block at
// ((rfrag*KS + kstep)*64 + lane)*8; lane's 16 B chunk = its mfma operand.
DEV void store_xh(ushort_t* __restrict__ H, ushort_t* __restrict__ L,
                  int b, int k, float v)
{
    size_t idx = (((size_t)(b >> 4) * 40 + (k >> 5)) * 64
                  + ((k >> 3) & 3) * 16 + (b & 15)) * 8 + (k & 7);
    ushort_t hb = f2bf(v);
    H[idx] = hb;
    L[idx] = f2bf(v - bf2f(hb));
}

// ---------------------------------------------------------------------------
// fp32 tiled GEMM (h0/c0 + enc_proj fallback). OUTBF emits bf16.
// ---------------------------------------------------------------------------
template<int BN, int TM, int TN, int ACT1, int OUTBF>
__global__ __launch_bounds__(256)
void gemm_k(const float* __restrict__ A, int lda,
            const float* __restrict__ Wk, int ldw,
            const float* __restrict__ bias,
            void* __restrict__ Cv, long long ldc,
            int M, int N, int K)
{
    constexpr int BM = 64, BK = 16;
    constexpr int TX = BN / TN, TY = BM / TM;
    static_assert(TX * TY == 256, "bad tile config");
    __shared__ float As[BK][BM];
    __shared__ float Ws[BK][BN];

    const int tid = threadIdx.x;
    const int tx = tid % TX, ty = tid / TX;
    const int nb = blockIdx.x * BN, mb = blockIdx.y * BM;

    float acc[TM][TN] = {};
    const int am = tid >> 2;
    const int ak = (tid & 3) * 4;
    const int wn = tid % BN;
    const int wk0 = tid / BN;
    constexpr int WKSTEP = 256 / BN;

    for (int k0 = 0; k0 < K; k0 += BK) {
        float4 av = *(const float4*)&A[(size_t)(mb + am) * lda + k0 + ak];
        As[ak + 0][am] = av.x;
        As[ak + 1][am] = av.y;
        As[ak + 2][am] = av.z;
        As[ak + 3][am] = av.w;
        #pragma unroll
        for (int i = 0; i < BK / WKSTEP; ++i) {
            int kw = wk0 + i * WKSTEP;
            Ws[kw][wn] = (nb + wn < N) ? Wk[(size_t)(k0 + kw) * ldw + nb + wn] : 0.f;
        }
        __syncthreads();
        #pragma unroll
        for (int k = 0; k < BK; ++k) {
            float a[TM], w[TN];
            #pragma unroll
            for (int i = 0; i < TM; ++i) a[i] = As[k][ty * TM + i];
            #pragma unroll
            for (int j = 0; j < TN; ++j) w[j] = Ws[k][tx * TN + j];
            #pragma unroll
            for (int i = 0; i < TM; ++i)
                #pragma unroll
                for (int j = 0; j < TN; ++j)
                    acc[i][j] = fmaf(a[i], w[j], acc[i][j]);
        }
        __syncthreads();
    }

    #pragma unroll
    for (int i = 0; i < TM; ++i) {
        int m = mb + ty * TM + i;
        #pragma unroll
        for (int j = 0; j < TN; ++j) {
            int n = nb + tx * TN + j;
            if (n < N) {
                float v = acc[i][j];
                if (bias) v += bias[n];
                if (ACT1 == 1) v = tanh_f(v);
                if (OUTBF) ((ushort_t*)Cv)[(size_t)m * ldc + n] = f2bf(v);
                else       ((float*)Cv)[(size_t)m * ldc + n] = v;
            }
        }
    }
}

// ---------------------------------------------------------------------------
// Packed-fragment MFMA GEMM with register double-buffer prefetch.
// SPLIT: 1 = Ahi*Bhi; 2 = +Alo*Bhi; 3 = +Ahi*Blo.
// W2D: 2x2 wave grid (block tile 2MT x 2NT frags); else 4 waves along N.
// PERM: C row m = t*128+b -> out[b][t][:] (nontemporal fp32).
// OUTBF: bf16 output at row*ldc+nc.
// XSWZ: 1D grid, bijective XCD swizzle; l1=lin/bdiv, l2=lin%bdiv;
//       NMINOR ? (bx=l2, by=l1) : (bx=l1, by=l2).
// ---------------------------------------------------------------------------
template<int MT, int NT, int ACT1, int ACT2, int SPLIT, bool OUTBF, bool PERM,
         bool XSWZ, bool NMINOR, bool W2D>
__global__ __launch_bounds__(256)
void mgemm_pk(const ushort_t* __restrict__ AH, const ushort_t* __restrict__ AL, int aFS,
              const ushort_t* __restrict__ BH, const ushort_t* __restrict__ BL, int bFS,
              const float* __restrict__ bias, const float* __restrict__ bias2, int N1,
              void* __restrict__ Cv, long long ldc, long long ldc2,
              int Nfrags, int Ntot, int nsteps, int bdiv)
{
    int bx, by;
    if (XSWZ) {
        int nwg = gridDim.x, orig = blockIdx.x;
        int xcd = orig & 7, idx = orig >> 3;
        int q = nwg >> 3, r = nwg & 7;
        int lin = (xcd < r ? xcd * (q + 1) : r * (q + 1) + (xcd - r) * q) + idx;
        int l1 = lin / bdiv, l2 = lin - l1 * bdiv;
        bx = NMINOR ? l2 : l1;
        by = NMINOR ? l1 : l2;
    } else { bx = blockIdx.x; by = blockIdx.y; }

    const int wv = threadIdx.x >> 6, lane = threadIdx.x & 63;
    int nf0, mf0;
    if (W2D) {
        nf0 = (bx * 2 + (wv & 1)) * NT;
        mf0 = by * (2 * MT) + (wv >> 1) * MT;
    } else {
        nf0 = (bx * 4 + wv) * NT;
        mf0 = by * MT;
    }
    if (nf0 >= Nfrags) return;
    const int col = lane & 15;
    const int lofs = lane * 8;

    const ushort_t *paH[MT], *paL[MT], *pbH[NT], *pbL[NT];
    #pragma unroll
    for (int mt = 0; mt < MT; ++mt) {
        paH[mt] = AH + (size_t)(mf0 + mt) * aFS + lofs;
        paL[mt] = (SPLIT >= 2) ? (AL + (size_t)(mf0 + mt) * aFS + lofs) : paH[mt];
    }
    #pragma unroll
    for (int ct = 0; ct < NT; ++ct) {
        int nf = nf0 + ct; if (nf > Nfrags - 1) nf = Nfrags - 1;
        pbH[ct] = BH + (size_t)nf * bFS + lofs;
        pbL[ct] = (SPLIT == 3) ? (BL + (size_t)nf * bFS + lofs) : pbH[ct];
    }

    f32x4 acc[MT][NT];
    #pragma unroll
    for (int mt = 0; mt < MT; ++mt)
        #pragma unroll
        for (int ct = 0; ct < NT; ++ct) acc[mt][ct] = (f32x4){0.f, 0.f, 0.f, 0.f};

    auto LOADF = [&](bf16x8 (&A0)[MT], bf16x8 (&A1)[MT],
                     bf16x8 (&B0)[NT], bf16x8 (&B1)[NT], int i) {
        size_t o = (size_t)i * 512;
        #pragma unroll
        for (int mt = 0; mt < MT; ++mt) {
            A0[mt] = *(const bf16x8*)(paH[mt] + o);
            if (SPLIT >= 2) A1[mt] = *(const bf16x8*)(paL[mt] + o);
        }
        #pragma unroll
        for (int ct = 0; ct < NT; ++ct) {
            B0[ct] = *(const bf16x8*)(pbH[ct] + o);
            if (SPLIT == 3) B1[ct] = *(const bf16x8*)(pbL[ct] + o);
        }
    };
    auto COMPF = [&](bf16x8 (&A0)[MT], bf16x8 (&A1)[MT],
                     bf16x8 (&B0)[NT], bf16x8 (&B1)[NT]) {
        #pragma unroll
        for (int mt = 0; mt < MT; ++mt)
            #pragma unroll
            for (int ct = 0; ct < NT; ++ct) {
                acc[mt][ct] = __builtin_amdgcn_mfma_f32_16x16x32_bf16(A0[mt], B0[ct], acc[mt][ct], 0, 0, 0);
                if (SPLIT >= 2)
                    acc[mt][ct] = __builtin_amdgcn_mfma_f32_16x16x32_bf16(A1[mt], B0[ct], acc[mt][ct], 0, 0, 0);
                if (SPLIT == 3)
                    acc[mt][ct] = __builtin_amdgcn_mfma_f32_16x16x32_bf16(A0[mt], B1[ct], acc[mt][ct], 0, 0, 0);
            }
    };

    bf16x8 xa0[MT], xa1[MT], xb0[NT], xb1[NT];
    bf16x8 ya0[MT], ya1[MT], yb0[NT], yb1[NT];
    LOADF(xa0, xa1, xb0, xb1, 0);
    for (int i = 0; i < nsteps; i += 2) {
        LOADF(ya0, ya1, yb0, yb1, i + 1);
        COMPF(xa0, xa1, xb0, xb1);
        if (i + 2 < nsteps) LOADF(xa0, xa1, xb0, xb1, i + 2);
        COMPF(ya0, ya1, yb0, yb1);
    }

    #pragma unroll
    for (int ct = 0; ct < NT; ++ct) {
        const int nc = (nf0 + ct) * 16 + col;
        if (nc >= Ntot) continue;
        const bool ns = ((nf0 + ct) * 16 >= N1);
        float bv = ns ? (bias2 ? bias2[nc - N1] : 0.f) : (bias ? bias[nc] : 0.f);
        const int act = ns ? ACT2 : ACT1;
        #pragma unroll
        for (int mt = 0; mt < MT; ++mt)
            #pragma unroll
            for (int r = 0; r < 4; ++r) {
                int row = (mf0 + mt) * 16 + (lane >> 4) * 4 + r;
                float v = acc[mt][ct][r] + bv;
                if (act == 1)      v = tanh_f(v);
                else if (act == 2) v = sigm_f(v);
                size_t off = PERM ? ((size_t)(row & 127) * ldc + (size_t)(row >> 7) * ldc2 + nc)
                                  : ((size_t)row * ldc + nc);
                if (OUTBF)      ((ushort_t*)Cv)[off] = f2bf(v);
                else if (PERM)  __builtin_nontemporal_store(v, &((float*)Cv)[off]);
                else            ((float*)Cv)[off] = v;
            }
    }
}

// ---------------------------------------------------------------------------
// Fused gates GEMM + LSTM. gates = [x|h] @ Wg^T + bcomb; then elementwise.
// Block: 32 rows (2 m-frags) x 16 j-cols (1 j-frag; 4 gate-frags at nf stride 32).
// Grid (32 j-frags, 4 m-quarters). 4 waves K-split (10 k-steps each of 40).
// All 4 gates of a (b,j) cell land in the SAME lane -> in-register LSTM.
// ---------------------------------------------------------------------------
template<bool BLO>
__global__ __launch_bounds__(256)
void gates_lstm_k(const ushort_t* __restrict__ AH, const ushort_t* __restrict__ AL,
                  const ushort_t* __restrict__ BH, const ushort_t* __restrict__ BL,
                  const float* __restrict__ bcomb, float* __restrict__ c,
                  ushort_t* __restrict__ xhi, ushort_t* __restrict__ xlo,
                  ushort_t* __restrict__ hseqH, ushort_t* __restrict__ hseqL, int t)
{
    constexpr int FS = 40 * 512, KPW = 10;
    const int wv = threadIdx.x >> 6, lane = threadIdx.x & 63;
    const int jf = blockIdx.x;      // 0..31
    const int mq = blockIdx.y;      // 0..3
    const int ks0 = wv * KPW;
    const int lofs = lane * 8;

    const ushort_t *paH[2], *paL[2], *pbH[4], *pbL[4];
    #pragma unroll
    for (int mt = 0; mt < 2; ++mt) {
        size_t off = (size_t)(mq * 2 + mt) * FS + (size_t)ks0 * 512 + lofs;
        paH[mt] = AH + off; paL[mt] = AL + off;
    }
    #pragma unroll
    for (int g = 0; g < 4; ++g) {
        size_t off = (size_t)(g * 32 + jf) * FS + (size_t)ks0 * 512 + lofs;
        pbH[g] = BH + off;
        pbL[g] = BLO ? (BL + off) : (BH + off);
    }

    f32x4 acc[2][4];
    #pragma unroll
    for (int mt = 0; mt < 2; ++mt)
        #pragma unroll
        for (int g = 0; g < 4; ++g) acc[mt][g] = (f32x4){0.f, 0.f, 0.f, 0.f};

    auto LOADF = [&](bf16x8 (&A)[2][2], bf16x8 (&B)[4][2], int i) {
        size_t o = (size_t)i * 512;
        #pragma unroll
        for (int mt = 0; mt < 2; ++mt) {
            A[mt][0] = *(const bf16x8*)(paH[mt] + o);
            A[mt][1] = *(const bf16x8*)(paL[mt] + o);
        }
        #pragma unroll
        for (int g = 0; g < 4; ++g) {
            B[g][0] = *(const bf16x8*)(pbH[g] + o);
            if (BLO) B[g][1] = *(const bf16x8*)(pbL[g] + o);
        }
    };
    auto COMPF = [&](bf16x8 (&A)[2][2], bf16x8 (&B)[4][2]) {
        #pragma unroll
        for (int mt = 0; mt < 2; ++mt)
            #pragma unroll
            for (int g = 0; g < 4; ++g) {
                acc[mt][g] = __builtin_amdgcn_mfma_f32_16x16x32_bf16(A[mt][0], B[g][0], acc[mt][g], 0, 0, 0);
                acc[mt][g] = __builtin_amdgcn_mfma_f32_16x16x32_bf16(A[mt][1], B[g][0], acc[mt][g], 0, 0, 0);
                if (BLO)
                    acc[mt][g] = __builtin_amdgcn_mfma_f32_16x16x32_bf16(A[mt][0], B[g][1], acc[mt][g], 0, 0, 0);
            }
    };

    bf16x8 xA[2][2], xB[4][2], yA[2][2], yB[4][2];
    LOADF(xA, xB, 0);
    for (int i = 0; i < KPW; i += 2) {
        LOADF(yA, yB, i + 1);
        COMPF(xA, xB);
        if (i + 2 < KPW) LOADF(xA, xB, i + 2);
        COMPF(yA, yB);
    }

    __shared__ f32x4 part[3][2][4][64];
    if (wv > 0) {
        #pragma unroll
        for (int mt = 0; mt < 2; ++mt)
            #pragma unroll
            for (int g = 0; g < 4; ++g) part[wv - 1][mt][g][lane] = acc[mt][g];
    }
    __syncthreads();
    if (wv == 0) {
        #pragma unroll
        for (int mt = 0; mt < 2; ++mt)
            #pragma unroll
            for (int g = 0; g < 4; ++g) {
                acc[mt][g] += part[0][mt][g][lane];
                acc[mt][g] += part[1][mt][g][lane];
                acc[mt][g] += part[2][mt][g][lane];
            }
        const int j = jf * 16 + (lane & 15);
        float bi = bcomb[j], bf = bcomb[512 + j];
        float bg = bcomb[1024 + j], bo = bcomb[1536 + j];
        #pragma unroll
        for (int mt = 0; mt < 2; ++mt)
            #pragma unroll
            for (int r = 0; r < 4; ++r) {
                int b = mq * 32 + mt * 16 + (lane >> 4) * 4 + r;
                float ig = sigm_f(acc[mt][0][r] + bi);
                float fg = sigm_f(acc[mt][1][r] + bf);
                float gg = tanh_f(acc[mt][2][r] + bg);
                float og = sigm_f(acc[mt][3][r] + bo);
                float cn = fg * c[b * 512 + j] + ig * gg;
                c[b * 512 + j] = cn;
                float hv = og * tanh_f(cn);
                store_xh(xhi, xlo, b, 768 + j, hv);
                ushort_t hb = f2bf(hv);
                size_t hidx = (((size_t)(t * 8 + (b >> 4)) * 16 + (j >> 5)) * 64
                               + ((j >> 3) & 3) * 16 + (b & 15)) * 8 + (j & 7);
                hseqH[hidx] = hb;
                hseqL[hidx] = f2bf(hv - bf2f(hb));
            }
    }
}

// ---------------------------------------------------------------------------
// Weight transpose+convert into PACKED-FRAGMENT layout.
// ---------------------------------------------------------------------------
template<bool LO>
__global__ __launch_bounds__(256)
void convT_pk(const float* __restrict__ W, int N, int KSr,
              ushort_t* __restrict__ PH, ushort_t* __restrict__ PL,
              int KSfull, int ksOfs, int nfOfs)
{
    int tid = blockIdx.x * 256 + threadIdx.x;
    int lane = tid & 63;
    int rest = tid >> 6;
    int ks = rest % KSr;
    int nf = rest / KSr;
    const float* src = W + (size_t)(ks * 32 + ((lane >> 4) & 3) * 8) * N
                         + nf * 16 + (lane & 15);
    size_t dbase = (((size_t)(nf + nfOfs) * KSfull + ks + ksOfs) * 64 + lane) * 8;
    #pragma unroll
    for (int jj = 0; jj < 8; ++jj) {
        float v = src[(size_t)jj * N];
        ushort_t h = f2bf(v);
        PH[dbase + jj] = h;
        if (LO) PL[dbase + jj] = f2bf(v - bf2f(h));
    }
}

// ---------------------------------------------------------------------------
// img fp32 [25088][512] -> linear bf16 hi + packed-fragment bf16 hi.
// One thread per (rf, ks, lane); grid = 1568*16*64/256 = 6272.
// ---------------------------------------------------------------------------
__global__ __launch_bounds__(256)
void convimg_k(const float* __restrict__ img, ushort_t* __restrict__ linH,
               ushort_t* __restrict__ pkH)
{
    int tid = blockIdx.x * 256 + threadIdx.x;
    int lane = tid & 63;
    int rest = tid >> 6;
    int ks = rest & 15, rf = rest >> 4;
    int r = rf * 16 + (lane & 15);
    int k = ks * 32 + ((lane >> 4) & 3) * 8;
    const float* src = img + (size_t)r * 512 + k;
    ushort_t* ld = linH + (size_t)r * 512 + k;
    size_t pidx = (((size_t)rf * 16 + ks) * 64 + lane) * 8;
    #pragma unroll
    for (int jj = 0; jj < 8; ++jj) {
        ushort_t h = f2bf(src[jj]);
        ld[jj] = h;
        pkH[pidx + jj] = h;
    }
}

// elementwise fp32 -> bf16 (hi only) — fallback path
__global__ void convbf_k(const float* __restrict__ src, ushort_t* __restrict__ dst,
                         long long n)
{
    long long i = (long long)(blockIdx.x * 256 + threadIdx.x) * 4;
    long long stride = (long long)gridDim.x * 1024;
    for (; i + 3 < n; i += stride) {
        float4 v = *(const float4*)&src[i];
        dst[i + 0] = f2bf(v.x); dst[i + 1] = f2bf(v.y);
        dst[i + 2] = f2bf(v.z); dst[i + 3] = f2bf(v.w);
    }
}

// feat_mean
__global__ __launch_bounds__(256)
void featmean_k(const float* __restrict__ img, float* __restrict__ fm)
{
    int b = blockIdx.x, tid = threadIdx.x;
    const float* base = img + (size_t)b * Ll * ENCe;
    for (int e = tid; e < ENCe; e += 256) {
        float s = 0.f;
        for (int l = 0; l < Ll; ++l) s += base[l * ENCe + e];
        fm[b * ENCe + e] = s * (1.f / (float)Ll);
    }
}

__global__ void bcomb_k(const float* __restrict__ bih, const float* __restrict__ bhh,
                        float* __restrict__ bc)
{
    int i = blockIdx.x * 256 + threadIdx.x;
    if (i < 4 * Hh) bc[i] = bih[i] + bhh[i];
}

// h0 fp32 -> xh packed at col 768+j
__global__ void hconv_k(const float* __restrict__ h, ushort_t* __restrict__ xhi,
                        ushort_t* __restrict__ xlo)
{
    int i = blockIdx.x * 256 + threadIdx.x;
    if (i >= Bb * Hh) return;
    int b = i / Hh, j = i % Hh;
    store_xh(xhi, xlo, b, 768 + j, h[i]);
}

// ---------------------------------------------------------------------------
// Fused attention: per block b (512 threads = 8 waves):
//  score (tanh dot) -> softmax -> alphas out -> emb x[0:256] -> ctx*gate x[256:768]
// ---------------------------------------------------------------------------
template<bool IMGBF>
__global__ __launch_bounds__(512)
void attn_fused_k(const ushort_t* __restrict__ enc, const float* __restrict__ dgb,
                  const float* __restrict__ v_att,
                  const ushort_t* __restrict__ img_bf, const float* __restrict__ img_f,
                  const float* __restrict__ emb, const int* __restrict__ captions,
                  float* __restrict__ alphas, long long alpha_stride,
                  ushort_t* __restrict__ xhi, ushort_t* __restrict__ xlo, int t)
{
    int b = blockIdx.x, tid = threadIdx.x;
    __shared__ float dp[Hh], va[Hh], es[Ll], red[8];

    dp[tid] = dgb[b * 1024 + tid];
    va[tid] = v_att[tid];
    __syncthreads();

    int wv = tid >> 6, ln = tid & 63;
    const ushort_t* ep = enc + (size_t)b * Ll * Hh;
    for (int l = wv; l < Ll; l += 8) {
        const ushort_t* row = ep + (size_t)l * Hh;
        float s = 0.f;
        #pragma unroll
        for (int r = 0; r < 8; ++r) {
            int k = r * 64 + ln;
            s += tanh_f(bf2f(row[k]) + dp[k]) * va[k];
        }
        #pragma unroll
        for (int o = 32; o; o >>= 1) s += __shfl_xor(s, o);
        if (ln == 0) es[l] = s;
    }
    __syncthreads();

    float v = (tid < Ll) ? es[tid] : -1e30f;
    float m = v;
    #pragma unroll
    for (int o = 32; o; o >>= 1) m = fmaxf(m, __shfl_xor(m, o));
    if (ln == 0) red[wv] = m;
    __syncthreads();
    m = red[0];
    #pragma unroll
    for (int i = 1; i < 8; ++i) m = fmaxf(m, red[i]);
    __syncthreads();
    float p = (tid < Ll) ? __expf(v - m) : 0.f;
    float s = p;
    #pragma unroll
    for (int o = 32; o; o >>= 1) s += __shfl_xor(s, o);
    if (ln == 0) red[wv] = s;
    __syncthreads();
    s = 0.f;
    #pragma unroll
    for (int i = 0; i < 8; ++i) s += red[i];
    float inv = 1.f / s;
    if (tid < Ll) {
        float a = p * inv;
        es[tid] = a;
        alphas[(size_t)b * alpha_stride + tid] = a;
    }
    if (tid < Ee) {
        float xv = emb[(size_t)captions[b * Tt + t] * Ee + tid];
        store_xh(xhi, xlo, b, tid, xv);
    }
    __syncthreads();

    int e = tid;
    float acc = 0.f;
    if (IMGBF) {
        const ushort_t* ib = img_bf + (size_t)b * Ll * ENCe + e;
        #pragma unroll 4
        for (int l = 0; l < Ll; ++l) acc = fmaf(es[l], bf2f(ib[(size_t)l * ENCe]), acc);
    } else {
        const float* ib = img_f + (size_t)b * Ll * ENCe + e;
        #pragma unroll 4
        for (int l = 0; l < Ll; ++l) acc = fmaf(es[l], ib[(size_t)l * ENCe], acc);
    }
    float xv = acc * dgb[b * 1024 + 512 + e];
    store_xh(xhi, xlo, b, 256 + e, xv);
}

// ---------------------------------------------------------------------------
extern "C" void kernel_launch(void* const* d_in, const int* in_sizes, int n_in,
                              void* d_out, int out_size, void* d_ws, size_t ws_size,
                              hipStream_t stream)
{
    const float* img    = (const float*)d_in[0];
    const float* W_h    = (const float*)d_in[1];
    const float* b_h    = (const float*)d_in[2];
    const float* W_c    = (const float*)d_in[3];
    const float* b_c    = (const float*)d_in[4];
    const float* W_gate = (const float*)d_in[5];
    const float* b_gate = (const float*)d_in[6];
    const float* emb    = (const float*)d_in[7];
    const float* W_ae   = (const float*)d_in[8];
    const float* b_ae   = (const float*)d_in[9];
    const float* W_ad   = (const float*)d_in[10];
    const float* b_ad   = (const float*)d_in[11];
    const float* v_att  = (const float*)d_in[12];
    const float* W_ih   = (const float*)d_in[14];
    const float* b_ih   = (const float*)d_in[15];
    const float* W_hh   = (const float*)d_in[16];
    const float* b_hh   = (const float*)d_in[17];
    const float* W_out  = (const float*)d_in[18];
    const float* b_out  = (const float*)d_in[19];
    const int* captions = (const int*)d_in[20];

    float* out    = (float*)d_out;                       // [B,T,V]
    float* alphas = out + (size_t)Bb * Tt * Vv;          // [B,T,L]

    // ---- workspace allocator (256B aligned) ----
    char* p = (char*)d_ws;
    auto alloc = [&](size_t bytes) -> char* {
        char* r = p; p += (bytes + 255) & ~(size_t)255; return r;
    };
    const size_t szEnc   = (size_t)Bb * Ll * Hh * 2;      // 25.7 MB
    const size_t szWout  = (size_t)625 * 16 * 512 * 2;    // 10.24 MB (packed)
    const size_t szWg    = (size_t)128 * 40 * 512 * 2;    // 5.24 MB (packed)
    const size_t szWdg   = (size_t)64 * 16 * 512 * 2;     // 1.05 MB (packed)
    const size_t szWae   = (size_t)32 * 16 * 512 * 2;     // 0.52 MB (packed hi)
    const size_t szXh    = (size_t)8 * 40 * 512 * 2;      // 0.33 MB (packed)
    const size_t szHseq  = (size_t)160 * 16 * 512 * 2;    // 2.62 MB (packed)
    const size_t szImg   = (size_t)Bb * Ll * ENCe * 2;    // 25.7 MB

    ushort_t* enc_hi  = (ushort_t*)alloc(szEnc);
    ushort_t* WoutPkH = (ushort_t*)alloc(szWout);
    ushort_t* WgPkH   = (ushort_t*)alloc(szWg);
    ushort_t* WdgPkH  = (ushort_t*)alloc(szWdg);
    ushort_t* WaePkH  = (ushort_t*)alloc(szWae);
    ushort_t* xhPkH   = (ushort_t*)alloc(szXh);
    ushort_t* xhPkL   = (ushort_t*)alloc(szXh);
    ushort_t* hseqPkH = (ushort_t*)alloc(szHseq);
    ushort_t* hseqPkL = (ushort_t*)alloc(szHseq);
    float*    cbuf    = (float*)alloc((size_t)Bb * Hh * 4);
    float*    dgb     = (float*)alloc((size_t)Bb * 1024 * 4);
    float*    S       = (float*)alloc((size_t)Bb * 1024 * 4); // fm + h0
    float*    bcomb   = (float*)alloc(4 * Hh * 4);

    auto tryAlloc = [&](size_t bytes) -> char* {
        size_t used = (size_t)(p - (char*)d_ws);
        size_t rounded = (bytes + 255) & ~(size_t)255;
        if (used + rounded > ws_size) return nullptr;
        return alloc(bytes);
    };
    ushort_t* WoutPkL = (ushort_t*)tryAlloc(szWout);
    ushort_t* WgPkL   = (ushort_t*)tryAlloc(szWg);
    ushort_t* WdgPkL  = (ushort_t*)tryAlloc(szWdg);
    ushort_t* imgLin  = (ushort_t*)tryAlloc(szImg);   // linear bf16 hi (ctx)
    ushort_t* imgPk   = (ushort_t*)tryAlloc(szImg);   // packed bf16 hi (enc GEMM)

    float* fm  = S;                      // [B][512]
    float* h0b = S + Bb * ENCe;          // [B][512]

    dim3 blk(256);
    const int NOSPLIT = 0x40000000;
    const int aFSxh   = 40 * 512;
    const int aFSh    = 16 * 512;

    // ---- one-time weight conversion into packed-fragment bf16 ----
    if (WoutPkL) convT_pk<true ><<<2500, blk, 0, stream>>>(W_out, Vv, 16, WoutPkH, WoutPkL, 16, 0, 0);
    else         convT_pk<false><<<2500, blk, 0, stream>>>(W_out, Vv, 16, WoutPkH, nullptr, 16, 0, 0);
    if (WgPkL) {
        convT_pk<true ><<<768, blk, 0, stream>>>(W_ih, 2048, 24, WgPkH, WgPkL, 40, 0, 0);
        convT_pk<true ><<<512, blk, 0, stream>>>(W_hh, 2048, 16, WgPkH, WgPkL, 40, 24, 0);
    } else {
        convT_pk<false><<<768, blk, 0, stream>>>(W_ih, 2048, 24, WgPkH, nullptr, 40, 0, 0);
        convT_pk<false><<<512, blk, 0, stream>>>(W_hh, 2048, 16, WgPkH, nullptr, 40, 24, 0);
    }
    if (WdgPkL) {
        convT_pk<true ><<<128, blk, 0, stream>>>(W_ad,   Hh, 16, WdgPkH, WdgPkL, 16, 0, 0);
        convT_pk<true ><<<128, blk, 0, stream>>>(W_gate, Hh, 16, WdgPkH, WdgPkL, 16, 0, 32);
    } else {
        convT_pk<false><<<128, blk, 0, stream>>>(W_ad,   Hh, 16, WdgPkH, nullptr, 16, 0, 0);
        convT_pk<false><<<128, blk, 0, stream>>>(W_gate, Hh, 16, WdgPkH, nullptr, 16, 0, 32);
    }
    convT_pk<false><<<128, blk, 0, stream>>>(W_ae, Hh, 16, WaePkH, nullptr, 16, 0, 0);

    bcomb_k<<<(4 * Hh + 255) / 256, blk, 0, stream>>>(b_ih, b_hh, bcomb);
    featmean_k<<<Bb, blk, 0, stream>>>(img, fm);

    // h0 = tanh(fm @ W_h + b_h) ; c0 = tanh(fm @ W_c + b_c)
    gemm_k<32, 2, 4, 1, 0><<<dim3(Hh / 32, Bb / 64), blk, 0, stream>>>(
        fm, ENCe, W_h, Hh, b_h, h0b, Hh, Bb, Hh, ENCe);
    gemm_k<32, 2, 4, 1, 0><<<dim3(Hh / 32, Bb / 64), blk, 0, stream>>>(
        fm, ENCe, W_c, Hh, b_c, cbuf, Hh, Bb, Hh, ENCe);
    hconv_k<<<(Bb * Hh + 255) / 256, blk, 0, stream>>>(h0b, xhPkH, xhPkL);

    // enc_proj = img @ W_ae + b_ae -> bf16 [B*L][512]
    if (imgPk && imgLin) {
        convimg_k<<<6272, blk, 0, stream>>>(img, imgLin, imgPk);
        // packed hi-only GEMM: block tile 128x128, n-minor XCD swizzle (A L2-reuse)
        mgemm_pk<4, 4, 0, 0, 1, true, false, true, true, true><<<dim3(784), blk, 0, stream>>>(
            imgPk, nullptr, aFSh, WaePkH, nullptr, aFSh, b_ae, nullptr, NOSPLIT,
            enc_hi, Hh, 0, 32, Hh, 16, 4);
    } else {
        if (imgLin) convbf_k<<<2048, blk, 0, stream>>>(img, imgLin, (long long)Bb * Ll * ENCe);
        gemm_k<64, 4, 4, 0, 1><<<dim3(Hh / 64, (Bb * Ll) / 64), blk, 0, stream>>>(
            img, ENCe, W_ae, Hh, b_ae, enc_hi, Hh, Bb * Ll, Hh, ENCe);
    }

    for (int t = 0; t < Tt; ++t) {
        // dg = [h@W_ad + b_ad | sigmoid(h@W_gate + b_gate)]; A = xh ks 24..39
        if (WdgPkL)
            mgemm_pk<1, 1, 0, 2, 3, false, false, false, false, false><<<dim3(16, 8), blk, 0, stream>>>(
                xhPkH + 24 * 512, xhPkL + 24 * 512, aFSxh, WdgPkH, WdgPkL, aFSh,
                b_ad, b_gate, 512, dgb, 1024, 0, 64, 1024, 16, 0);
        else
            mgemm_pk<1, 1, 0, 2, 2, false, false, false, false, false><<<dim3(16, 8), blk, 0, stream>>>(
                xhPkH + 24 * 512, xhPkL + 24 * 512, aFSxh, WdgPkH, nullptr, aFSh,
                b_ad, b_gate, 512, dgb, 1024, 0, 64, 1024, 16, 0);

        if (imgLin)
            attn_fused_k<true ><<<Bb, dim3(512), 0, stream>>>(
                enc_hi, dgb, v_att, imgLin, nullptr, emb, captions,
                alphas + (size_t)t * Ll, (long long)Tt * Ll, xhPkH, xhPkL, t);
        else
            attn_fused_k<false><<<Bb, dim3(512), 0, stream>>>(
                enc_hi, dgb, v_att, nullptr, img, emb, captions,
                alphas + (size_t)t * Ll, (long long)Tt * Ll, xhPkH, xhPkL, t);

        // gates GEMM + fused LSTM
        if (WgPkL)
            gates_lstm_k<true ><<<dim3(32, 4), blk, 0, stream>>>(
                xhPkH, xhPkL, WgPkH, WgPkL, bcomb, cbuf,
                xhPkH, xhPkL, hseqPkH, hseqPkL, t);
        else
            gates_lstm_k<false><<<dim3(32, 4), blk, 0, stream>>>(
                xhPkH, xhPkL, WgPkH, nullptr, bcomb, cbuf,
                xhPkH, xhPkL, hseqPkH, hseqPkL, t);
    }

    // Batched logits: [2560, 10000] = hseq @ Wout^T + b_out -> out[b][t][v]
    if (WoutPkL)
        mgemm_pk<4, 4, 0, 0, 3, false, true, true, false, true><<<dim3(79 * 20), blk, 0, stream>>>(
            hseqPkH, hseqPkL, aFSh, WoutPkH, WoutPkL, aFSh,
            b_out, nullptr, NOSPLIT, out, (long long)Tt * Vv, (long long)Vv,
            625, Vv, 16, 20);
    else
        mgemm_pk<4, 4, 0, 0, 2, false, true, true, false, true><<<dim3(79 * 20), blk, 0, stream>>>(
            hseqPkH, hseqPkL, aFSh, WoutPkH, nullptr, aFSh,
            b_out, nullptr, NOSPLIT, out, (long long)Tt * Vv, (long long)Vv,
            625, Vv, 16, 20);
}